// Round 14
// baseline (847.860 us; speedup 1.0000x reference)
//
#include <hip/hip_runtime.h>
#include <hip/hip_bf16.h>
#include <cstdint>

#define BIGF 1e30f
constexpr int LB   = 4096;           // L = H*W
constexpr int NB   = 8;              // batch
constexpr int MROWS = NB * LB;       // 32768 pixel rows
constexpr int LSP  = 4104;           // level-start stride per batch

// ---------------- helpers ----------------
__device__ __forceinline__ float warp_sum(float v) {
#pragma unroll
  for (int off = 32; off; off >>= 1) v += __shfl_xor(v, off);
  return v;
}

__device__ __forceinline__ float block_sum256(float v) {
  __shared__ float sm[4];
  v = warp_sum(v);
  __syncthreads();
  if ((threadIdx.x & 63) == 0) sm[threadIdx.x >> 6] = v;
  __syncthreads();
  return sm[0] + sm[1] + sm[2] + sm[3];
}

// ---------------- LayerNorm over last dim 128 ----------------
__global__ __launch_bounds__(256) void ln128_kernel(
    const float* __restrict__ X, const float* __restrict__ g,
    const float* __restrict__ bb, float* __restrict__ O, float eps) {
  int wave = threadIdx.x >> 6, lane = threadIdx.x & 63;
  int row = blockIdx.x * 4 + wave;
  const float* xr = X + (size_t)row * 128;
  float x0 = xr[lane], x1 = xr[lane + 64];
  float mu = warp_sum(x0 + x1) * (1.0f / 128.0f);
  float d0 = x0 - mu, d1 = x1 - mu;
  float var = warp_sum(d0 * d0 + d1 * d1) * (1.0f / 128.0f);
  float s = 1.0f / sqrtf(var + eps);
  float* orow = O + (size_t)row * 128;
  orow[lane]      = d0 * s * g[lane]      + bb[lane];
  orow[lane + 64] = d1 * s * g[lane + 64] + bb[lane + 64];
}

// ---------------- f32 GEMM 64x64 tile (EPI 2: +addsrc, EPI 4: +bias+addsrc) ----------------
template<int EPI>
__global__ __launch_bounds__(256) void gemm_kernel(
    const float* __restrict__ A, const float* __restrict__ W,
    float* __restrict__ C, float* __restrict__ C2,
    const float* __restrict__ bias, const float* __restrict__ addsrc,
    int M, int N, int K) {
  __shared__ float As[32][68];
  __shared__ float Bs[32][68];
  int t = threadIdx.x;
  int tx = t & 15, ty = t >> 4;
  int bm = blockIdx.y * 64, bn = blockIdx.x * 64;
  float acc[4][4] = {};
  for (int k0 = 0; k0 < K; k0 += 32) {
#pragma unroll
    for (int hh = 0; hh < 2; ++hh) {
      int q = t + hh * 256;
      int r = q >> 3, kc = q & 7;
      float4 a4 = reinterpret_cast<const float4*>(A + (size_t)(bm + r) * K + k0)[kc];
      float4 b4 = reinterpret_cast<const float4*>(W + (size_t)(bn + r) * K + k0)[kc];
      As[kc * 4 + 0][r] = a4.x; As[kc * 4 + 1][r] = a4.y;
      As[kc * 4 + 2][r] = a4.z; As[kc * 4 + 3][r] = a4.w;
      Bs[kc * 4 + 0][r] = b4.x; Bs[kc * 4 + 1][r] = b4.y;
      Bs[kc * 4 + 2][r] = b4.z; Bs[kc * 4 + 3][r] = b4.w;
    }
    __syncthreads();
#pragma unroll
    for (int kk = 0; kk < 32; ++kk) {
      float4 av = *reinterpret_cast<const float4*>(&As[kk][ty * 4]);
      float4 bv = *reinterpret_cast<const float4*>(&Bs[kk][tx * 4]);
      float aa[4] = {av.x, av.y, av.z, av.w};
      float bbv[4] = {bv.x, bv.y, bv.z, bv.w};
#pragma unroll
      for (int i = 0; i < 4; ++i)
#pragma unroll
        for (int j = 0; j < 4; ++j) acc[i][j] += aa[i] * bbv[j];
    }
    __syncthreads();
  }
#pragma unroll
  for (int i = 0; i < 4; ++i) {
    int m = bm + ty * 4 + i;
#pragma unroll
    for (int j = 0; j < 4; ++j) {
      int n = bn + tx * 4 + j;
      float v = acc[i][j];
      if (EPI == 2) {
        C[(size_t)m * N + n] = v + addsrc[(size_t)m * N + n];
      } else if (EPI == 4) {
        C[(size_t)m * N + n] = v + bias[n] + addsrc[(size_t)m * N + n];
      }
    }
  }
}

// ---------------- f32 GEMM 128x128 tile (EPI 1: split+silu, EPI 3: +bias+gelu) ----------------
template<int EPI>
__global__ __launch_bounds__(256) void gemm128_kernel(
    const float* __restrict__ A, const float* __restrict__ W,
    float* __restrict__ C, float* __restrict__ C2,
    const float* __restrict__ bias, int M, int N, int K) {
  __shared__ float As[32][132];
  __shared__ float Bs[32][132];
  int t = threadIdx.x;
  int tx = t & 15, ty = t >> 4;
  int bm = blockIdx.y * 128, bn = blockIdx.x * 128;
  float acc[8][8] = {};
  for (int k0 = 0; k0 < K; k0 += 32) {
#pragma unroll
    for (int hh = 0; hh < 4; ++hh) {
      int q = t + hh * 256;
      int r = q >> 3, kc = q & 7;
      float4 a4 = *reinterpret_cast<const float4*>(A + (size_t)(bm + r) * K + k0 + kc * 4);
      float4 b4 = *reinterpret_cast<const float4*>(W + (size_t)(bn + r) * K + k0 + kc * 4);
      As[kc * 4 + 0][r] = a4.x; As[kc * 4 + 1][r] = a4.y;
      As[kc * 4 + 2][r] = a4.z; As[kc * 4 + 3][r] = a4.w;
      Bs[kc * 4 + 0][r] = b4.x; Bs[kc * 4 + 1][r] = b4.y;
      Bs[kc * 4 + 2][r] = b4.z; Bs[kc * 4 + 3][r] = b4.w;
    }
    __syncthreads();
#pragma unroll
    for (int kk = 0; kk < 32; ++kk) {
      float4 a0 = *reinterpret_cast<const float4*>(&As[kk][ty * 4]);
      float4 a1 = *reinterpret_cast<const float4*>(&As[kk][64 + ty * 4]);
      float4 b0 = *reinterpret_cast<const float4*>(&Bs[kk][tx * 4]);
      float4 b1 = *reinterpret_cast<const float4*>(&Bs[kk][64 + tx * 4]);
      float aa[8] = {a0.x, a0.y, a0.z, a0.w, a1.x, a1.y, a1.z, a1.w};
      float bb2[8] = {b0.x, b0.y, b0.z, b0.w, b1.x, b1.y, b1.z, b1.w};
#pragma unroll
      for (int i = 0; i < 8; ++i)
#pragma unroll
        for (int j = 0; j < 8; ++j) acc[i][j] += aa[i] * bb2[j];
    }
    __syncthreads();
  }
#pragma unroll
  for (int i = 0; i < 8; ++i) {
    int m = bm + (i >> 2) * 64 + ty * 4 + (i & 3);
#pragma unroll
    for (int j = 0; j < 8; ++j) {
      int n = bn + (j >> 2) * 64 + tx * 4 + (j & 3);
      float v = acc[i][j];
      if (EPI == 1) {
        if (n < 256) C[(size_t)m * 256 + n] = v;
        else C2[(size_t)m * 256 + (n - 256)] = v / (1.0f + __expf(-v));
      } else if (EPI == 3) {
        float u = v + bias[n];
        float xg = 1.5957691216057308f * (u + 0.044715f * u * u * u);
        C[(size_t)m * N + n] = u / (1.0f + __expf(-xg));   // 0.5u(1+tanh(.)) = u*sigmoid(2.)
      }
    }
  }
}

// ---------------- depthwise conv3x3 + silu + x_dbl/dts/deltaA/feat ----------------
// feat/dA written TRANSPOSED: [b][group=d>>2][node][d&3]
__global__ __launch_bounds__(256) void convfeat_kernel(
    const float* __restrict__ xcpre, const float* __restrict__ cw,
    const float* __restrict__ xw, const float* __restrict__ dtw,
    const float* __restrict__ dtb, const float* __restrict__ alogs,
    float* __restrict__ xs, float* __restrict__ dAt, float* __restrict__ featt,
    float* __restrict__ Cs, float* __restrict__ ssq) {
  int m = blockIdx.x;
  int d = threadIdx.x;
  int l = m & (LB - 1), b = m >> 12;
  int r = l >> 6, c = l & 63;
  float acc = 0.f;
#pragma unroll
  for (int ky = 0; ky < 3; ++ky) {
    int rr = r + ky - 1;
    if (rr < 0 || rr > 63) continue;
#pragma unroll
    for (int kx = 0; kx < 3; ++kx) {
      int cc = c + kx - 1;
      if (cc < 0 || cc > 63) continue;
      int ml = (b << 12) + (rr << 6) + cc;
      acc += xcpre[(size_t)ml * 256 + d] * cw[d * 9 + ky * 3 + kx];
    }
  }
  float xv = acc / (1.0f + __expf(-acc));        // silu
  xs[(size_t)m * 256 + d] = xv;
  float p[11];
#pragma unroll
  for (int i = 0; i < 10; ++i) p[i] = xv * xw[i * 256 + d];
  p[10] = xv * xv;
  __shared__ float sm[4][11];
#pragma unroll
  for (int i = 0; i < 11; ++i) p[i] = warp_sum(p[i]);
  int wv = d >> 6;
  if ((d & 63) == 0) {
    for (int i = 0; i < 11; ++i) sm[wv][i] = p[i];
  }
  __syncthreads();
  float red[11];
#pragma unroll
  for (int i = 0; i < 11; ++i) red[i] = sm[0][i] + sm[1][i] + sm[2][i] + sm[3][i];
  float xdt = dtb[d];
#pragma unroll
  for (int rr2 = 0; rr2 < 8; ++rr2) xdt += red[rr2] * dtw[d * 8 + rr2];
  float sp = fmaxf(xdt, 0.f) + __logf(1.0f + __expf(-fabsf(xdt)));   // softplus
  float As_ = -__expf(alogs[d]);
  size_t tidx = ((size_t)(b * 64 + (d >> 2)) * 4096 + l) * 4 + (d & 3);
  dAt[tidx]   = __expf(sp * As_);
  featt[tidx] = sp * red[8] * xv;
  if (d == 0) { Cs[m] = red[9]; ssq[m] = red[10]; }
}

// ---------------- grid edge weights wr/wd (exact expf — MST weights must match ref tree) ----
__global__ __launch_bounds__(256) void gridw_kernel(
    const float* __restrict__ xs, const float* __restrict__ ssq,
    float* __restrict__ wrg, float* __restrict__ wdg) {
  int m = blockIdx.x, d = threadIdx.x;
  int l = m & (LB - 1);
  int r = l >> 6, c = l & 63;
  float a = xs[(size_t)m * 256 + d];
  float br = (c < 63) ? xs[(size_t)(m + 1) * 256 + d] : 0.f;
  float bd = (r < 63) ? xs[(size_t)(m + 64) * 256 + d] : 0.f;
  float s1 = warp_sum(a * br);
  float s2 = warp_sum(a * bd);
  __shared__ float sm[4][2];
  int wv = d >> 6;
  if ((d & 63) == 0) { sm[wv][0] = s1; sm[wv][1] = s2; }
  __syncthreads();
  if (d == 0) {
    float dotr = sm[0][0] + sm[1][0] + sm[2][0] + sm[3][0];
    float dotd = sm[0][1] + sm[1][1] + sm[2][1] + sm[3][1];
    float na = sqrtf(ssq[m]);
    float wrv = BIGF, wdv = BIGF;
    if (c < 63) { float den = fmaxf(na * sqrtf(ssq[m + 1]), 1e-8f);  wrv = expf(-(dotr / den)); }
    if (r < 63) { float den = fmaxf(na * sqrtf(ssq[m + 64]), 1e-8f); wdv = expf(-(dotd / den)); }
    wrg[m] = wrv; wdg[m] = wdv;
  }
}

// ---------------- Boruvka MST + Euler-tour rooting (O(log V)) + levels ----------------
// Output: topo32[pos] = node | childmask<<12 | par<<16 ; levs_g per batch.
// Directions: 0=N(-64), 1=W(-1), 2=E(+1), 3=S(+64); rev(d)=3-d.
__global__ __launch_bounds__(1024) void mst_kernel(
    const float* __restrict__ wr_g, const float* __restrict__ wd_g,
    unsigned int* __restrict__ topo_g, int* __restrict__ levs_g) {
  __shared__ int pool[24592];          // 98.4 KB, phase-overlaid
  __shared__ unsigned char flagR[4096];
  __shared__ unsigned char flagD[4096];
  __shared__ int ncomp_s;
  __shared__ int wred[16];
  int b = blockIdx.x, tid = threadIdx.x;
  // ---- phase A layout (Boruvka) ----
  float* wrs = (float*)pool;
  float* wds = (float*)(pool + 4096);
  int* comp = pool + 8192;
  int* lnk  = pool + 12288;
  unsigned int* bestw = (unsigned int*)(pool + 16384);
  int* beste = pool + 20480;
  const float* wrb = wr_g + b * 4096;
  const float* wdb = wd_g + b * 4096;
  for (int k = 0; k < 4; ++k) {
    int i = tid + k * 1024;
    wrs[i] = wrb[i]; wds[i] = wdb[i];
    comp[i] = i; flagR[i] = 0; flagD[i] = 0;
  }
  __syncthreads();
  for (int phase = 0; phase < 13; ++phase) {
    for (int k = 0; k < 4; ++k) {
      int c = tid + k * 1024;
      bestw[c] = 0xFFFFFFFFu; beste[c] = 0x7FFFFFFF; lnk[c] = c;
    }
    if (tid == 0) ncomp_s = 0;
    __syncthreads();
    for (int k = 0; k < 8; ++k) {
      int e = tid + k * 1024;
      int v = e & 4095;
      bool isR = e < 4096;
      int c = v & 63, r = v >> 6;
      bool valid = isR ? (c < 63) : (r < 63);
      if (valid) {
        int u = isR ? v + 1 : v + 64;
        int ca = comp[v], cb = comp[u];
        if (ca != cb) {
          unsigned wbits = __float_as_uint(isR ? wrs[v] : wds[v]);
          atomicMin(&bestw[ca], wbits);
          atomicMin(&bestw[cb], wbits);
        }
      }
    }
    __syncthreads();
    for (int k = 0; k < 8; ++k) {
      int e = tid + k * 1024;
      int v = e & 4095;
      bool isR = e < 4096;
      int c = v & 63, r = v >> 6;
      bool valid = isR ? (c < 63) : (r < 63);
      if (valid) {
        int u = isR ? v + 1 : v + 64;
        int ca = comp[v], cb = comp[u];
        if (ca != cb) {
          unsigned wbits = __float_as_uint(isR ? wrs[v] : wds[v]);
          if (wbits == bestw[ca]) atomicMin(&beste[ca], e);
          if (wbits == bestw[cb]) atomicMin(&beste[cb], e);
        }
      }
    }
    __syncthreads();
    for (int k = 0; k < 4; ++k) {
      int cc = tid + k * 1024;
      int e = beste[cc];
      if (e != 0x7FFFFFFF) {
        int v = e & 4095;
        bool isR = e < 4096;
        int u = isR ? v + 1 : v + 64;
        if (isR) flagR[v] = 1; else flagD[v] = 1;
        int ca = comp[v], cb = comp[u];
        lnk[cc] = (ca == cc) ? cb : ca;
      }
    }
    __syncthreads();
    for (int k = 0; k < 4; ++k) {
      int cc = tid + k * 1024;
      int l = lnk[cc];
      if (l != cc && lnk[l] == cc && cc < l) lnk[cc] = cc;
    }
    __syncthreads();
    for (int it = 0; it < 12; ++it) {
      for (int k = 0; k < 4; ++k) {
        int cc = tid + k * 1024;
        lnk[cc] = lnk[lnk[cc]];
      }
      __syncthreads();
    }
    for (int k = 0; k < 4; ++k) {
      int i = tid + k * 1024;
      comp[i] = lnk[comp[i]];
      if (comp[i] == i) atomicAdd(&ncomp_s, 1);
    }
    __syncthreads();
    if (ncomp_s <= 1) break;
    __syncthreads();
  }
  // ---- phase B layout (Euler tour; overlays dead Boruvka arrays) ----
  unsigned short* nxt = (unsigned short*)pool;        // [16400]
  short*          dsv = (short*)(pool + 8200);        // [16400]
  int* par = pool + 16400;                            // [4096]
  int* dep = pool + 20496;                            // [4096]
  const int NIL = 16384;
  unsigned short rn[16];
  int rd[16];
  int validm = 0;
  for (int k = 0; k < 4; ++k) { int i = tid + k * 1024; par[i] = 0; dep[i] = 0; }
#pragma unroll
  for (int k = 0; k < 16; ++k) {
    int a = tid + k * 1024;
    int u = a >> 2, d = a & 3;
    int c = u & 63, r = u >> 6;
    int mu = 0;
    if (r > 0  && flagD[u - 64]) mu |= 1;
    if (c > 0  && flagR[u - 1])  mu |= 2;
    if (c < 63 && flagR[u])      mu |= 4;
    if (r < 63 && flagD[u])      mu |= 8;
    unsigned short nx = NIL; short dv = 0;
    if (mu & (1 << d)) {
      validm |= 1 << k;
      int v = u + ((d == 0) ? -64 : (d == 1) ? -1 : (d == 2) ? 1 : 64);
      int cv = v & 63, rv = v >> 6;
      int mv = 0;
      if (rv > 0  && flagD[v - 64]) mv |= 1;
      if (cv > 0  && flagR[v - 1])  mv |= 2;
      if (cv < 63 && flagR[v])      mv |= 4;
      if (rv < 63 && flagD[v])      mv |= 8;
      int din = 3 - d;
      int hi = mv >> (din + 1);
      int dn = hi ? (din + __ffs(hi)) : (__ffs(mv) - 1);
      int nxv = v * 4 + dn;
      int m0 = (flagR[0] ? 4 : 0) | (flagD[0] ? 8 : 0);
      int a0 = __ffs(m0) - 1;                 // start arc (root node 0)
      if (v == 0 && nxv == a0) nxv = NIL;     // break circuit before start
      nx = (unsigned short)nxv;
      dv = 1;
    }
    nxt[a] = nx; dsv[a] = dv;
    rn[k] = nx; rd[k] = dv;
  }
  if (tid == 0) { nxt[NIL] = NIL; dsv[NIL] = 0; }
  __syncthreads();
#pragma unroll 1
  for (int it = 0; it < 13; ++it) {
    unsigned short nn[16]; short nd[16];
#pragma unroll
    for (int k = 0; k < 16; ++k) { nn[k] = nxt[rn[k]]; nd[k] = dsv[rn[k]]; }
    __syncthreads();
#pragma unroll
    for (int k = 0; k < 16; ++k) {
      int a = tid + k * 1024;
      rd[k] += nd[k];
      rn[k] = nn[k];
      nxt[a] = rn[k]; dsv[a] = (short)rd[k];
    }
    __syncthreads();
  }
#pragma unroll
  for (int k = 0; k < 16; ++k) if (validm & (1 << k)) {
    int a = tid + k * 1024;
    int u = a >> 2, d = a & 3;
    int v = u + ((d == 0) ? -64 : (d == 1) ? -1 : (d == 2) ? 1 : 64);
    int rb = v * 4 + (3 - d);
    if (rd[k] > (int)dsv[rb]) par[v] = u;
  }
  __syncthreads();
#pragma unroll
  for (int k = 0; k < 16; ++k) {
    int a = tid + k * 1024;
    int u = a >> 2, d = a & 3;
    unsigned short nx = NIL; short dv = 0;
    if (validm & (1 << k)) {
      int v = u + ((d == 0) ? -64 : (d == 1) ? -1 : (d == 2) ? 1 : 64);
      int cv = v & 63, rv = v >> 6;
      int mv = 0;
      if (rv > 0  && flagD[v - 64]) mv |= 1;
      if (cv > 0  && flagR[v - 1])  mv |= 2;
      if (cv < 63 && flagR[v])      mv |= 4;
      if (rv < 63 && flagD[v])      mv |= 8;
      int din = 3 - d;
      int hi = mv >> (din + 1);
      int dn = hi ? (din + __ffs(hi)) : (__ffs(mv) - 1);
      int nxv = v * 4 + dn;
      int m0 = (flagR[0] ? 4 : 0) | (flagD[0] ? 8 : 0);
      int a0 = __ffs(m0) - 1;
      if (v == 0 && nxv == a0) nxv = NIL;
      nx = (unsigned short)nxv;
      dv = (par[v] == u) ? (short)1 : (short)-1;
    }
    nxt[a] = nx; dsv[a] = dv;
    rn[k] = nx; rd[k] = dv;
  }
  __syncthreads();
#pragma unroll 1
  for (int it = 0; it < 13; ++it) {
    unsigned short nn[16]; short nd[16];
#pragma unroll
    for (int k = 0; k < 16; ++k) { nn[k] = nxt[rn[k]]; nd[k] = dsv[rn[k]]; }
    __syncthreads();
#pragma unroll
    for (int k = 0; k < 16; ++k) {
      int a = tid + k * 1024;
      rd[k] += nd[k];
      rn[k] = nn[k];
      nxt[a] = rn[k]; dsv[a] = (short)rd[k];
    }
    __syncthreads();
  }
#pragma unroll
  for (int k = 0; k < 16; ++k) if (validm & (1 << k)) {
    int a = tid + k * 1024;
    int u = a >> 2, d = a & 3;
    int v = u + ((d == 0) ? -64 : (d == 1) ? -1 : (d == 2) ? 1 : 64);
    if (par[v] == u) dep[v] = 1 - rd[k];
  }
  __syncthreads();
  // ---- max depth ----
  int md = 0;
  for (int k = 0; k < 4; ++k) md = max(md, dep[tid + k * 1024]);
#pragma unroll
  for (int off = 32; off; off >>= 1) md = max(md, __shfl_xor(md, off));
  if ((tid & 63) == 0) wred[tid >> 6] = md;
  __syncthreads();
  if (tid == 0) {
    int m = 0;
    for (int i = 0; i < 16; ++i) m = max(m, wred[i]);
    wred[0] = m;
  }
  __syncthreads();
  int maxd = wred[0];
  __syncthreads();
  // ---- histogram + exclusive prefix over depth buckets ----
  int* cnt  = pool;
  int* offs = pool + 4096;
  for (int k = 0; k < 4; ++k) cnt[tid + k * 1024] = 0;
  __syncthreads();
  for (int k = 0; k < 4; ++k) atomicAdd(&cnt[dep[tid + k * 1024]], 1);
  __syncthreads();
  int base4 = tid * 4;
  int c0 = cnt[base4], c1 = cnt[base4 + 1], c2 = cnt[base4 + 2], c3 = cnt[base4 + 3];
  int tsum = c0 + c1 + c2 + c3;
  int lane = tid & 63, wid = tid >> 6;
  int iv = tsum;
  for (int off = 1; off < 64; off <<= 1) {
    int n = __shfl_up(iv, off);
    if (lane >= off) iv += n;
  }
  if (lane == 63) wred[wid] = iv;
  __syncthreads();
  if (tid == 0) {
    int acc = 0;
    for (int i = 0; i < 16; ++i) { int t = wred[i]; wred[i] = acc; acc += t; }
  }
  __syncthreads();
  int excl = iv - tsum + wred[wid];
  offs[base4]     = excl;
  offs[base4 + 1] = excl + c0;
  offs[base4 + 2] = excl + c0 + c1;
  offs[base4 + 3] = excl + c0 + c1 + c2;
  __syncthreads();
  for (int idx = tid; idx <= maxd; idx += 1024) levs_g[b * LSP + idx] = offs[idx];
  if (tid == 0) {
    levs_g[b * LSP + maxd + 1] = 4096;
    levs_g[b * LSP + 4098] = maxd + 1;
  }
  __syncthreads();   // levs_g copy must finish reading offs before scatter mutates it
  // ---- scatter: topo32[pos] = node | childmask<<12 | par<<16 ----
  for (int k = 0; k < 4; ++k) {
    int v2 = tid + k * 1024;
    int pos = atomicAdd(&offs[dep[v2]], 1);
    int c = v2 & 63, r = v2 >> 6;
    unsigned msk = 0;
    if (r > 0  && par[v2 - 64] == v2) msk |= 1;
    if (c > 0  && par[v2 - 1]  == v2) msk |= 2;
    if (c < 63 && par[v2 + 1]  == v2) msk |= 4;
    if (r < 63 && par[v2 + 64] == v2) msk |= 8;
    topo_g[b * 4096 + pos] =
        (unsigned)v2 | (msk << 12) | ((unsigned)par[v2] << 16);
  }
}

// ---------------- scan v4: 72KB LDS, 4-stage pipeline (topo 3 ahead, el 2 ahead) ----------------
// 512 blocks x 64 threads, 2 blocks/CU -> all resident -> single scheduling round.
__global__ __launch_bounds__(64) void scan_kernel(
    float* __restrict__ buft, const float* __restrict__ ewt,
    const unsigned int* __restrict__ topo_g, const int* __restrict__ levs_g) {
  __shared__ float acc[16384];           // [node*4 + ch], 64 KB
  __shared__ unsigned short lvs[4104];   // 8 KB
  int bid = blockIdx.x;
  int b = bid >> 6, cg = bid & 63;
  int lane = threadIdx.x;
  int ch = lane & 3, slot = lane >> 2;
  int nlev = levs_g[b * LSP + 4098];
  size_t fbase = (size_t)(b * 64 + cg) * 16384;
  const float4* bt4 = reinterpret_cast<const float4*>(buft + fbase);
  const float*  ewf = ewt + fbase;
  const float4* et4 = reinterpret_cast<const float4*>(ewf);
  const unsigned int* tp = topo_g + b * 4096;
  // ---- stage acc=f (coalesced); warm ew slab into L2 ----
  float4* acc4 = reinterpret_cast<float4*>(acc);
  float wsum = 0.f;
  for (int n = lane; n < 4096; n += 64) {
    acc4[n] = bt4[n];
    float4 ev = et4[n];
    wsum += ev.x + ev.y + ev.z + ev.w;
  }
  asm volatile("" :: "v"(wsum));         // keep warming reads live
  for (int i = lane; i <= nlev; i += 64) lvs[i] = (unsigned short)levs_g[b * LSP + i];
  __syncthreads();
  // ======== UP: levels nlev-1 .. 1 (scatter child -> parent) ========
  if (nlev > 1) {
    int lev0 = nlev - 1;
    int jA = lvs[lev0] + slot, eA = lvs[lev0 + 1];
    unsigned tA = tp[jA < 4096 ? jA : 4095];
    float elA = ewf[(tA & 4095) * 4 + ch];
    int jB = 0, eB = 0; unsigned tB = 0; float elB = 0.f;
    if (lev0 - 1 >= 1) {
      jB = lvs[lev0 - 1] + slot; eB = lvs[lev0];
      tB = tp[jB < 4096 ? jB : 4095];
      elB = ewf[(tB & 4095) * 4 + ch];
    }
    int jC = 0, eC = 0; unsigned tC = 0;
    if (lev0 - 2 >= 1) {
      jC = lvs[lev0 - 2] + slot; eC = lvs[lev0 - 1];
      tC = tp[jC < 4096 ? jC : 4095];
    }
    for (int lev = lev0; lev >= 1; --lev) {
      // issue el(C) [2 levels ahead], topo(D) [3 levels ahead]
      float elC = 0.f;
      if (lev - 2 >= 1) elC = ewf[(tC & 4095) * 4 + ch];
      int jD = 0, eD = 0; unsigned tD = 0;
      if (lev - 3 >= 1) {
        jD = lvs[lev - 3] + slot; eD = lvs[lev - 2];
        tD = tp[jD < 4096 ? jD : 4095];
      }
      // process level A
      if (jA < eA) {
        int vA = tA & 4095, pA = (tA >> 16) & 4095;
        float a = acc[vA * 4 + ch];
        atomicAdd(&acc[pA * 4 + ch], elA * a);
        for (int j = jA + 16; j < eA; j += 16) {       // big levels (rare)
          unsigned t = tp[j];
          int v = t & 4095, p = (t >> 16) & 4095;
          float e = ewf[v * 4 + ch];
          float av = acc[v * 4 + ch];
          atomicAdd(&acc[p * 4 + ch], e * av);
        }
      }
      __builtin_amdgcn_wave_barrier();
      // rotate A<-B<-C<-D
      jA = jB; eA = eB; tA = tB; elA = elB;
      jB = jC; eB = eC; tB = tC; elB = elC;
      jC = jD; eC = eD; tC = tD;
    }
  }
  __builtin_amdgcn_wave_barrier();
  // ======== DOWN: levels 1 .. nlev-1 ========
  if (nlev > 1) {
    int jA = lvs[1] + slot, eA = lvs[2];
    unsigned tA = tp[jA < 4096 ? jA : 4095];
    float elA = ewf[(tA & 4095) * 4 + ch];
    int jB = 0, eB = 0; unsigned tB = 0; float elB = 0.f;
    if (2 < nlev) {
      jB = lvs[2] + slot; eB = lvs[3];
      tB = tp[jB < 4096 ? jB : 4095];
      elB = ewf[(tB & 4095) * 4 + ch];
    }
    int jC = 0, eC = 0; unsigned tC = 0;
    if (3 < nlev) {
      jC = lvs[3] + slot; eC = lvs[4];
      tC = tp[jC < 4096 ? jC : 4095];
    }
    for (int lev = 1; lev < nlev; ++lev) {
      // issue el(C) [2 ahead], topo(D) [3 ahead]
      float elC = 0.f;
      if (lev + 2 < nlev) elC = ewf[(tC & 4095) * 4 + ch];
      int jD = 0, eD = 0; unsigned tD = 0;
      if (lev + 3 < nlev) {
        jD = lvs[lev + 3] + slot; eD = lvs[lev + 4];
        tD = tp[jD < 4096 ? jD : 4095];
      }
      // process level A
      if (jA < eA) {
        int vA = tA & 4095, pA = (tA >> 16) & 4095;
        float uv = acc[vA * 4 + ch];
        float pb = acc[pA * 4 + ch];
        acc[vA * 4 + ch] = uv + elA * (pb - elA * uv);
        for (int j = jA + 16; j < eA; j += 16) {       // big levels (rare)
          unsigned t = tp[j];
          int v = t & 4095, p = (t >> 16) & 4095;
          float e = ewf[v * 4 + ch];
          float uvv = acc[v * 4 + ch];
          float pbv = acc[p * 4 + ch];
          acc[v * 4 + ch] = uvv + e * (pbv - e * uvv);
        }
      }
      __builtin_amdgcn_wave_barrier();
      // rotate
      jA = jB; eA = eB; tA = tB; elA = elB;
      jB = jC; eB = eC; tB = tC; elB = elC;
      jC = jD; eC = eD; tC = tD;
    }
  }
  __syncthreads();
  // ---- write back (coalesced) ----
  float4* bw4 = reinterpret_cast<float4*>(buft + fbase);
  for (int n = lane; n < 4096; n += 64) bw4[n] = acc4[n];
}

// ---------------- post-scan: LN(d=256) -> *Cs + ds*xs -> LN -> *z ----------------
__global__ __launch_bounds__(256) void post_kernel(
    const float* __restrict__ buft, const float* __restrict__ Cs,
    const float* __restrict__ xs, const float* __restrict__ ds,
    const float* __restrict__ hng, const float* __restrict__ hnb,
    const float* __restrict__ ong, const float* __restrict__ onb,
    float* __restrict__ zya) {
  int m = blockIdx.x, d = threadIdx.x;
  int b = m >> 12, l = m & (LB - 1);
  size_t idx = (size_t)m * 256 + d;
  float fo = buft[((size_t)(b * 64 + (d >> 2)) * 4096 + l) * 4 + (d & 3)];
  float mu = block_sum256(fo) * (1.f / 256.f);
  float dv = fo - mu;
  float var = block_sum256(dv * dv) * (1.f / 256.f);
  float ho = dv * (1.0f / sqrtf(var + 1e-5f)) * hng[d] + hnb[d];
  float y = ho * Cs[m] + ds[d] * xs[idx];
  float mu2 = block_sum256(y) * (1.f / 256.f);
  float dy = y - mu2;
  float var2 = block_sum256(dy * dy) * (1.f / 256.f);
  float y2 = dy * (1.0f / sqrtf(var2 + 1e-5f)) * ong[d] + onb[d];
  zya[idx] = y2 * zya[idx];     // ya = y * z (in place over z)
}

// ---------------- launcher ----------------
extern "C" void kernel_launch(void* const* d_in, const int* in_sizes, int n_in,
                              void* d_out, int out_size, void* d_ws, size_t ws_size,
                              hipStream_t stream) {
  (void)in_sizes; (void)n_in; (void)out_size; (void)ws_size;
  const float* x      = (const float*)d_in[0];
  const float* ln1g   = (const float*)d_in[1];
  const float* ln1b   = (const float*)d_in[2];
  const float* ln2g   = (const float*)d_in[3];
  const float* ln2b   = (const float*)d_in[4];
  const float* w_in   = (const float*)d_in[5];
  const float* conv_w = (const float*)d_in[6];
  const float* xw     = (const float*)d_in[7];
  const float* dtw    = (const float*)d_in[8];
  const float* dtb    = (const float*)d_in[9];
  const float* alogs  = (const float*)d_in[10];
  const float* dsv    = (const float*)d_in[11];
  const float* hng    = (const float*)d_in[12];
  const float* hnb    = (const float*)d_in[13];
  const float* ong    = (const float*)d_in[14];
  const float* onb    = (const float*)d_in[15];
  const float* w_out  = (const float*)d_in[16];
  const float* mw1    = (const float*)d_in[17];
  const float* mb1    = (const float*)d_in[18];
  const float* mw2    = (const float*)d_in[19];
  const float* mb2    = (const float*)d_in[20];

  char* ws = (char*)d_ws;
  float* h    = (float*)(ws + 0);            // 16MB (h, later x1)
  float* z    = (float*)(ws + 16777216);     // 33.5MB (z, later ya in-place)
  float* xcp  = (float*)(ws + 50331648);     // 33.5MB (xc_pre, later h2)
  float* xs   = (float*)(ws + 83886080);     // 33.5MB
  float* dAt  = (float*)(ws + 117440512);    // 33.5MB transposed deltaA
  float* featt= (float*)(ws + 150994944);    // 33.5MB transposed feat -> scan buf
  float* Cs   = (float*)(ws + 184549376);
  float* ssq  = (float*)(ws + 184680448);
  float* wr   = (float*)(ws + 184811520);
  float* wd   = (float*)(ws + 184942592);
  unsigned int* topo32 = (unsigned int*)(ws + 185073664);   // 128KB
  int*   levs = (int*)(ws + 185335808);
  float* midg = xs;      // 67MB spans xs+dAt (both dead by then)
  float* x1   = h;
  float* h2   = xcp;

  ln128_kernel<<<MROWS / 4, 256, 0, stream>>>(x, ln1g, ln1b, h, 1e-6f);
  gemm128_kernel<1><<<dim3(4, 256), 256, 0, stream>>>(h, w_in, xcp, z, nullptr,
                                                      MROWS, 512, 128);
  convfeat_kernel<<<MROWS, 256, 0, stream>>>(xcp, conv_w, xw, dtw, dtb, alogs,
                                             xs, dAt, featt, Cs, ssq);
  gridw_kernel<<<MROWS, 256, 0, stream>>>(xs, ssq, wr, wd);
  mst_kernel<<<NB, 1024, 0, stream>>>(wr, wd, topo32, levs);
  scan_kernel<<<512, 64, 0, stream>>>(featt, dAt, topo32, levs);
  post_kernel<<<MROWS, 256, 0, stream>>>(featt, Cs, xs, dsv, hng, hnb, ong, onb, z);
  gemm_kernel<2><<<dim3(2, 512), 256, 0, stream>>>(z, w_out, x1, nullptr, nullptr, x,
                                                   MROWS, 128, 256);
  ln128_kernel<<<MROWS / 4, 256, 0, stream>>>(x1, ln2g, ln2b, h2, 1e-6f);
  gemm128_kernel<3><<<dim3(4, 256), 256, 0, stream>>>(h2, mw1, midg, nullptr, mb1,
                                                      MROWS, 512, 128);
  gemm_kernel<4><<<dim3(2, 512), 256, 0, stream>>>(midg, mw2, (float*)d_out, nullptr,
                                                   mb2, x1, MROWS, 128, 512);
}

// Round 15
// 833.503 us; speedup vs baseline: 1.0172x; 1.0172x over previous
//
#include <hip/hip_runtime.h>
#include <hip/hip_bf16.h>
#include <cstdint>

#define BIGF 1e30f
constexpr int LB   = 4096;           // L = H*W
constexpr int NB   = 8;              // batch
constexpr int MROWS = NB * LB;       // 32768 pixel rows
constexpr int LSP  = 4104;           // level-start stride per batch

// ---------------- helpers ----------------
__device__ __forceinline__ float warp_sum(float v) {
#pragma unroll
  for (int off = 32; off; off >>= 1) v += __shfl_xor(v, off);
  return v;
}

// ---------------- f32 GEMM 64x64 tile (EPI 2: +addsrc, EPI 4: +bias+addsrc) ----------------
template<int EPI>
__global__ __launch_bounds__(256) void gemm_kernel(
    const float* __restrict__ A, const float* __restrict__ W,
    float* __restrict__ C, float* __restrict__ C2,
    const float* __restrict__ bias, const float* __restrict__ addsrc,
    int M, int N, int K) {
  __shared__ float As[32][68];
  __shared__ float Bs[32][68];
  int t = threadIdx.x;
  int tx = t & 15, ty = t >> 4;
  int bm = blockIdx.y * 64, bn = blockIdx.x * 64;
  float acc[4][4] = {};
  for (int k0 = 0; k0 < K; k0 += 32) {
#pragma unroll
    for (int hh = 0; hh < 2; ++hh) {
      int q = t + hh * 256;
      int r = q >> 3, kc = q & 7;
      float4 a4 = reinterpret_cast<const float4*>(A + (size_t)(bm + r) * K + k0)[kc];
      float4 b4 = reinterpret_cast<const float4*>(W + (size_t)(bn + r) * K + k0)[kc];
      As[kc * 4 + 0][r] = a4.x; As[kc * 4 + 1][r] = a4.y;
      As[kc * 4 + 2][r] = a4.z; As[kc * 4 + 3][r] = a4.w;
      Bs[kc * 4 + 0][r] = b4.x; Bs[kc * 4 + 1][r] = b4.y;
      Bs[kc * 4 + 2][r] = b4.z; Bs[kc * 4 + 3][r] = b4.w;
    }
    __syncthreads();
#pragma unroll
    for (int kk = 0; kk < 32; ++kk) {
      float4 av = *reinterpret_cast<const float4*>(&As[kk][ty * 4]);
      float4 bv = *reinterpret_cast<const float4*>(&Bs[kk][tx * 4]);
      float aa[4] = {av.x, av.y, av.z, av.w};
      float bbv[4] = {bv.x, bv.y, bv.z, bv.w};
#pragma unroll
      for (int i = 0; i < 4; ++i)
#pragma unroll
        for (int j = 0; j < 4; ++j) acc[i][j] += aa[i] * bbv[j];
    }
    __syncthreads();
  }
#pragma unroll
  for (int i = 0; i < 4; ++i) {
    int m = bm + ty * 4 + i;
#pragma unroll
    for (int j = 0; j < 4; ++j) {
      int n = bn + tx * 4 + j;
      float v = acc[i][j];
      if (EPI == 2) {
        C[(size_t)m * N + n] = v + addsrc[(size_t)m * N + n];
      } else if (EPI == 4) {
        C[(size_t)m * N + n] = v + bias[n] + addsrc[(size_t)m * N + n];
      }
    }
  }
}

// ------- f32 GEMM 128x128 tile with FUSED LayerNorm on A (EPI 1: split+silu, EPI 3: +bias+gelu) -------
// A is the raw (pre-LN) activation; LN(g,b,eps=1e-6) applied during staging.
template<int EPI>
__global__ __launch_bounds__(256) void gemm128ln_kernel(
    const float* __restrict__ A, const float* __restrict__ W,
    float* __restrict__ C, float* __restrict__ C2,
    const float* __restrict__ bias, const float* __restrict__ lng,
    const float* __restrict__ lnb, int M, int N, int K) {
  __shared__ float As[32][132];
  __shared__ float Bs[32][132];
  __shared__ float mu_s[128], rs_s[128], g_s[128], b_s[128];
  int t = threadIdx.x;
  int tx = t & 15, ty = t >> 4;
  int bm = blockIdx.y * 128, bn = blockIdx.x * 128;
  // ---- row stats (two-pass; rows bm..bm+128) ----
  {
    int r = t >> 1, hf = t & 1;
    const float4* row = reinterpret_cast<const float4*>(A + (size_t)(bm + r) * K + hf * 64);
    float s = 0.f;
#pragma unroll
    for (int i = 0; i < 16; ++i) { float4 v = row[i]; s += v.x + v.y + v.z + v.w; }
    s += __shfl_xor(s, 1);
    float mu = s * (1.0f / 128.0f);
    float sq = 0.f;
#pragma unroll
    for (int i = 0; i < 16; ++i) {
      float4 v = row[i];
      float d0 = v.x - mu, d1 = v.y - mu, d2 = v.z - mu, d3 = v.w - mu;
      sq += d0 * d0 + d1 * d1 + d2 * d2 + d3 * d3;
    }
    sq += __shfl_xor(sq, 1);
    if (hf == 0) {
      mu_s[r] = mu;
      rs_s[r] = 1.0f / sqrtf(sq * (1.0f / 128.0f) + 1e-6f);
    }
    if (t < 128) { g_s[t] = lng[t]; b_s[t] = lnb[t]; }
  }
  __syncthreads();
  float acc[8][8] = {};
  for (int k0 = 0; k0 < K; k0 += 32) {
#pragma unroll
    for (int hh = 0; hh < 4; ++hh) {
      int q = t + hh * 256;
      int r = q >> 3, kc = q & 7;
      float4 a4 = *reinterpret_cast<const float4*>(A + (size_t)(bm + r) * K + k0 + kc * 4);
      float4 b4 = *reinterpret_cast<const float4*>(W + (size_t)(bn + r) * K + k0 + kc * 4);
      float mu = mu_s[r], rs = rs_s[r];
      int c0 = k0 + kc * 4;
      As[kc * 4 + 0][r] = (a4.x - mu) * rs * g_s[c0]     + b_s[c0];
      As[kc * 4 + 1][r] = (a4.y - mu) * rs * g_s[c0 + 1] + b_s[c0 + 1];
      As[kc * 4 + 2][r] = (a4.z - mu) * rs * g_s[c0 + 2] + b_s[c0 + 2];
      As[kc * 4 + 3][r] = (a4.w - mu) * rs * g_s[c0 + 3] + b_s[c0 + 3];
      Bs[kc * 4 + 0][r] = b4.x; Bs[kc * 4 + 1][r] = b4.y;
      Bs[kc * 4 + 2][r] = b4.z; Bs[kc * 4 + 3][r] = b4.w;
    }
    __syncthreads();
#pragma unroll
    for (int kk = 0; kk < 32; ++kk) {
      float4 a0 = *reinterpret_cast<const float4*>(&As[kk][ty * 4]);
      float4 a1 = *reinterpret_cast<const float4*>(&As[kk][64 + ty * 4]);
      float4 b0 = *reinterpret_cast<const float4*>(&Bs[kk][tx * 4]);
      float4 b1 = *reinterpret_cast<const float4*>(&Bs[kk][64 + tx * 4]);
      float aa[8] = {a0.x, a0.y, a0.z, a0.w, a1.x, a1.y, a1.z, a1.w};
      float bb2[8] = {b0.x, b0.y, b0.z, b0.w, b1.x, b1.y, b1.z, b1.w};
#pragma unroll
      for (int i = 0; i < 8; ++i)
#pragma unroll
        for (int j = 0; j < 8; ++j) acc[i][j] += aa[i] * bb2[j];
    }
    __syncthreads();
  }
#pragma unroll
  for (int i = 0; i < 8; ++i) {
    int m = bm + (i >> 2) * 64 + ty * 4 + (i & 3);
#pragma unroll
    for (int j = 0; j < 8; ++j) {
      int n = bn + (j >> 2) * 64 + tx * 4 + (j & 3);
      float v = acc[i][j];
      if (EPI == 1) {
        if (n < 256) C[(size_t)m * 256 + n] = v;
        else C2[(size_t)m * 256 + (n - 256)] = v / (1.0f + __expf(-v));
      } else if (EPI == 3) {
        float u = v + bias[n];
        float xg = 1.5957691216057308f * (u + 0.044715f * u * u * u);
        C[(size_t)m * N + n] = u / (1.0f + __expf(-xg));   // 0.5u(1+tanh(.)) = u*sigmoid(2.)
      }
    }
  }
}

// ---------------- depthwise conv3x3 + silu + x_dbl/dts/deltaA/feat ----------------
// feat/dA written TRANSPOSED: [b][group=d>>2][node][d&3]
__global__ __launch_bounds__(256) void convfeat_kernel(
    const float* __restrict__ xcpre, const float* __restrict__ cw,
    const float* __restrict__ xw, const float* __restrict__ dtw,
    const float* __restrict__ dtb, const float* __restrict__ alogs,
    float* __restrict__ xs, float* __restrict__ dAt, float* __restrict__ featt,
    float* __restrict__ Cs, float* __restrict__ ssq) {
  int m = blockIdx.x;
  int d = threadIdx.x;
  int l = m & (LB - 1), b = m >> 12;
  int r = l >> 6, c = l & 63;
  float acc = 0.f;
#pragma unroll
  for (int ky = 0; ky < 3; ++ky) {
    int rr = r + ky - 1;
    if (rr < 0 || rr > 63) continue;
#pragma unroll
    for (int kx = 0; kx < 3; ++kx) {
      int cc = c + kx - 1;
      if (cc < 0 || cc > 63) continue;
      int ml = (b << 12) + (rr << 6) + cc;
      acc += xcpre[(size_t)ml * 256 + d] * cw[d * 9 + ky * 3 + kx];
    }
  }
  float xv = acc / (1.0f + __expf(-acc));        // silu
  xs[(size_t)m * 256 + d] = xv;
  float p[11];
#pragma unroll
  for (int i = 0; i < 10; ++i) p[i] = xv * xw[i * 256 + d];
  p[10] = xv * xv;
  __shared__ float sm[4][11];
#pragma unroll
  for (int i = 0; i < 11; ++i) p[i] = warp_sum(p[i]);
  int wv = d >> 6;
  if ((d & 63) == 0) {
    for (int i = 0; i < 11; ++i) sm[wv][i] = p[i];
  }
  __syncthreads();
  float red[11];
#pragma unroll
  for (int i = 0; i < 11; ++i) red[i] = sm[0][i] + sm[1][i] + sm[2][i] + sm[3][i];
  float xdt = dtb[d];
#pragma unroll
  for (int rr2 = 0; rr2 < 8; ++rr2) xdt += red[rr2] * dtw[d * 8 + rr2];
  float sp = fmaxf(xdt, 0.f) + __logf(1.0f + __expf(-fabsf(xdt)));   // softplus
  float As_ = -__expf(alogs[d]);
  size_t tidx = ((size_t)(b * 64 + (d >> 2)) * 4096 + l) * 4 + (d & 3);
  dAt[tidx]   = __expf(sp * As_);
  featt[tidx] = sp * red[8] * xv;
  if (d == 0) { Cs[m] = red[9]; ssq[m] = red[10]; }
}

// ---------------- grid edge weights wr/wd (exact expf — MST weights must match ref tree) ----
__global__ __launch_bounds__(256) void gridw_kernel(
    const float* __restrict__ xs, const float* __restrict__ ssq,
    float* __restrict__ wrg, float* __restrict__ wdg) {
  int m = blockIdx.x, d = threadIdx.x;
  int l = m & (LB - 1);
  int r = l >> 6, c = l & 63;
  float a = xs[(size_t)m * 256 + d];
  float br = (c < 63) ? xs[(size_t)(m + 1) * 256 + d] : 0.f;
  float bd = (r < 63) ? xs[(size_t)(m + 64) * 256 + d] : 0.f;
  float s1 = warp_sum(a * br);
  float s2 = warp_sum(a * bd);
  __shared__ float sm[4][2];
  int wv = d >> 6;
  if ((d & 63) == 0) { sm[wv][0] = s1; sm[wv][1] = s2; }
  __syncthreads();
  if (d == 0) {
    float dotr = sm[0][0] + sm[1][0] + sm[2][0] + sm[3][0];
    float dotd = sm[0][1] + sm[1][1] + sm[2][1] + sm[3][1];
    float na = sqrtf(ssq[m]);
    float wrv = BIGF, wdv = BIGF;
    if (c < 63) { float den = fmaxf(na * sqrtf(ssq[m + 1]), 1e-8f);  wrv = expf(-(dotr / den)); }
    if (r < 63) { float den = fmaxf(na * sqrtf(ssq[m + 64]), 1e-8f); wdv = expf(-(dotd / den)); }
    wrg[m] = wrv; wdg[m] = wdv;
  }
}

// ---------------- Boruvka MST + Euler-tour rooting (O(log V)) + levels ----------------
// Output: topo32[pos] = node | childmask<<12 | par<<16 ; levs_g per batch.
__global__ __launch_bounds__(1024) void mst_kernel(
    const float* __restrict__ wr_g, const float* __restrict__ wd_g,
    unsigned int* __restrict__ topo_g, int* __restrict__ levs_g) {
  __shared__ int pool[24592];          // 98.4 KB, phase-overlaid
  __shared__ unsigned char flagR[4096];
  __shared__ unsigned char flagD[4096];
  __shared__ int ncomp_s;
  __shared__ int wred[16];
  int b = blockIdx.x, tid = threadIdx.x;
  float* wrs = (float*)pool;
  float* wds = (float*)(pool + 4096);
  int* comp = pool + 8192;
  int* lnk  = pool + 12288;
  unsigned int* bestw = (unsigned int*)(pool + 16384);
  int* beste = pool + 20480;
  const float* wrb = wr_g + b * 4096;
  const float* wdb = wd_g + b * 4096;
  for (int k = 0; k < 4; ++k) {
    int i = tid + k * 1024;
    wrs[i] = wrb[i]; wds[i] = wdb[i];
    comp[i] = i; flagR[i] = 0; flagD[i] = 0;
  }
  __syncthreads();
  for (int phase = 0; phase < 13; ++phase) {
    for (int k = 0; k < 4; ++k) {
      int c = tid + k * 1024;
      bestw[c] = 0xFFFFFFFFu; beste[c] = 0x7FFFFFFF; lnk[c] = c;
    }
    if (tid == 0) ncomp_s = 0;
    __syncthreads();
    for (int k = 0; k < 8; ++k) {
      int e = tid + k * 1024;
      int v = e & 4095;
      bool isR = e < 4096;
      int c = v & 63, r = v >> 6;
      bool valid = isR ? (c < 63) : (r < 63);
      if (valid) {
        int u = isR ? v + 1 : v + 64;
        int ca = comp[v], cb = comp[u];
        if (ca != cb) {
          unsigned wbits = __float_as_uint(isR ? wrs[v] : wds[v]);
          atomicMin(&bestw[ca], wbits);
          atomicMin(&bestw[cb], wbits);
        }
      }
    }
    __syncthreads();
    for (int k = 0; k < 8; ++k) {
      int e = tid + k * 1024;
      int v = e & 4095;
      bool isR = e < 4096;
      int c = v & 63, r = v >> 6;
      bool valid = isR ? (c < 63) : (r < 63);
      if (valid) {
        int u = isR ? v + 1 : v + 64;
        int ca = comp[v], cb = comp[u];
        if (ca != cb) {
          unsigned wbits = __float_as_uint(isR ? wrs[v] : wds[v]);
          if (wbits == bestw[ca]) atomicMin(&beste[ca], e);
          if (wbits == bestw[cb]) atomicMin(&beste[cb], e);
        }
      }
    }
    __syncthreads();
    for (int k = 0; k < 4; ++k) {
      int cc = tid + k * 1024;
      int e = beste[cc];
      if (e != 0x7FFFFFFF) {
        int v = e & 4095;
        bool isR = e < 4096;
        int u = isR ? v + 1 : v + 64;
        if (isR) flagR[v] = 1; else flagD[v] = 1;
        int ca = comp[v], cb = comp[u];
        lnk[cc] = (ca == cc) ? cb : ca;
      }
    }
    __syncthreads();
    for (int k = 0; k < 4; ++k) {
      int cc = tid + k * 1024;
      int l = lnk[cc];
      if (l != cc && lnk[l] == cc && cc < l) lnk[cc] = cc;
    }
    __syncthreads();
    for (int it = 0; it < 12; ++it) {
      for (int k = 0; k < 4; ++k) {
        int cc = tid + k * 1024;
        lnk[cc] = lnk[lnk[cc]];
      }
      __syncthreads();
    }
    for (int k = 0; k < 4; ++k) {
      int i = tid + k * 1024;
      comp[i] = lnk[comp[i]];
      if (comp[i] == i) atomicAdd(&ncomp_s, 1);
    }
    __syncthreads();
    if (ncomp_s <= 1) break;
    __syncthreads();
  }
  // ---- Euler tour ----
  unsigned short* nxt = (unsigned short*)pool;        // [16400]
  short*          dsv = (short*)(pool + 8200);        // [16400]
  int* par = pool + 16400;                            // [4096]
  int* dep = pool + 20496;                            // [4096]
  const int NIL = 16384;
  unsigned short rn[16];
  int rd[16];
  int validm = 0;
  for (int k = 0; k < 4; ++k) { int i = tid + k * 1024; par[i] = 0; dep[i] = 0; }
#pragma unroll
  for (int k = 0; k < 16; ++k) {
    int a = tid + k * 1024;
    int u = a >> 2, d = a & 3;
    int c = u & 63, r = u >> 6;
    int mu = 0;
    if (r > 0  && flagD[u - 64]) mu |= 1;
    if (c > 0  && flagR[u - 1])  mu |= 2;
    if (c < 63 && flagR[u])      mu |= 4;
    if (r < 63 && flagD[u])      mu |= 8;
    unsigned short nx = NIL; short dv = 0;
    if (mu & (1 << d)) {
      validm |= 1 << k;
      int v = u + ((d == 0) ? -64 : (d == 1) ? -1 : (d == 2) ? 1 : 64);
      int cv = v & 63, rv = v >> 6;
      int mv = 0;
      if (rv > 0  && flagD[v - 64]) mv |= 1;
      if (cv > 0  && flagR[v - 1])  mv |= 2;
      if (cv < 63 && flagR[v])      mv |= 4;
      if (rv < 63 && flagD[v])      mv |= 8;
      int din = 3 - d;
      int hi = mv >> (din + 1);
      int dn = hi ? (din + __ffs(hi)) : (__ffs(mv) - 1);
      int nxv = v * 4 + dn;
      int m0 = (flagR[0] ? 4 : 0) | (flagD[0] ? 8 : 0);
      int a0 = __ffs(m0) - 1;
      if (v == 0 && nxv == a0) nxv = NIL;
      nx = (unsigned short)nxv;
      dv = 1;
    }
    nxt[a] = nx; dsv[a] = dv;
    rn[k] = nx; rd[k] = dv;
  }
  if (tid == 0) { nxt[NIL] = NIL; dsv[NIL] = 0; }
  __syncthreads();
#pragma unroll 1
  for (int it = 0; it < 13; ++it) {
    unsigned short nn[16]; short nd[16];
#pragma unroll
    for (int k = 0; k < 16; ++k) { nn[k] = nxt[rn[k]]; nd[k] = dsv[rn[k]]; }
    __syncthreads();
#pragma unroll
    for (int k = 0; k < 16; ++k) {
      int a = tid + k * 1024;
      rd[k] += nd[k];
      rn[k] = nn[k];
      nxt[a] = rn[k]; dsv[a] = (short)rd[k];
    }
    __syncthreads();
  }
#pragma unroll
  for (int k = 0; k < 16; ++k) if (validm & (1 << k)) {
    int a = tid + k * 1024;
    int u = a >> 2, d = a & 3;
    int v = u + ((d == 0) ? -64 : (d == 1) ? -1 : (d == 2) ? 1 : 64);
    int rb = v * 4 + (3 - d);
    if (rd[k] > (int)dsv[rb]) par[v] = u;
  }
  __syncthreads();
#pragma unroll
  for (int k = 0; k < 16; ++k) {
    int a = tid + k * 1024;
    int u = a >> 2, d = a & 3;
    unsigned short nx = NIL; short dv = 0;
    if (validm & (1 << k)) {
      int v = u + ((d == 0) ? -64 : (d == 1) ? -1 : (d == 2) ? 1 : 64);
      int cv = v & 63, rv = v >> 6;
      int mv = 0;
      if (rv > 0  && flagD[v - 64]) mv |= 1;
      if (cv > 0  && flagR[v - 1])  mv |= 2;
      if (cv < 63 && flagR[v])      mv |= 4;
      if (rv < 63 && flagD[v])      mv |= 8;
      int din = 3 - d;
      int hi = mv >> (din + 1);
      int dn = hi ? (din + __ffs(hi)) : (__ffs(mv) - 1);
      int nxv = v * 4 + dn;
      int m0 = (flagR[0] ? 4 : 0) | (flagD[0] ? 8 : 0);
      int a0 = __ffs(m0) - 1;
      if (v == 0 && nxv == a0) nxv = NIL;
      nx = (unsigned short)nxv;
      dv = (par[v] == u) ? (short)1 : (short)-1;
    }
    nxt[a] = nx; dsv[a] = dv;
    rn[k] = nx; rd[k] = dv;
  }
  __syncthreads();
#pragma unroll 1
  for (int it = 0; it < 13; ++it) {
    unsigned short nn[16]; short nd[16];
#pragma unroll
    for (int k = 0; k < 16; ++k) { nn[k] = nxt[rn[k]]; nd[k] = dsv[rn[k]]; }
    __syncthreads();
#pragma unroll
    for (int k = 0; k < 16; ++k) {
      int a = tid + k * 1024;
      rd[k] += nd[k];
      rn[k] = nn[k];
      nxt[a] = rn[k]; dsv[a] = (short)rd[k];
    }
    __syncthreads();
  }
#pragma unroll
  for (int k = 0; k < 16; ++k) if (validm & (1 << k)) {
    int a = tid + k * 1024;
    int u = a >> 2, d = a & 3;
    int v = u + ((d == 0) ? -64 : (d == 1) ? -1 : (d == 2) ? 1 : 64);
    if (par[v] == u) dep[v] = 1 - rd[k];
  }
  __syncthreads();
  int md = 0;
  for (int k = 0; k < 4; ++k) md = max(md, dep[tid + k * 1024]);
#pragma unroll
  for (int off = 32; off; off >>= 1) md = max(md, __shfl_xor(md, off));
  if ((tid & 63) == 0) wred[tid >> 6] = md;
  __syncthreads();
  if (tid == 0) {
    int m = 0;
    for (int i = 0; i < 16; ++i) m = max(m, wred[i]);
    wred[0] = m;
  }
  __syncthreads();
  int maxd = wred[0];
  __syncthreads();
  int* cnt  = pool;
  int* offs = pool + 4096;
  for (int k = 0; k < 4; ++k) cnt[tid + k * 1024] = 0;
  __syncthreads();
  for (int k = 0; k < 4; ++k) atomicAdd(&cnt[dep[tid + k * 1024]], 1);
  __syncthreads();
  int base4 = tid * 4;
  int c0 = cnt[base4], c1 = cnt[base4 + 1], c2 = cnt[base4 + 2], c3 = cnt[base4 + 3];
  int tsum = c0 + c1 + c2 + c3;
  int lane = tid & 63, wid = tid >> 6;
  int iv = tsum;
  for (int off = 1; off < 64; off <<= 1) {
    int n = __shfl_up(iv, off);
    if (lane >= off) iv += n;
  }
  if (lane == 63) wred[wid] = iv;
  __syncthreads();
  if (tid == 0) {
    int acc = 0;
    for (int i = 0; i < 16; ++i) { int t = wred[i]; wred[i] = acc; acc += t; }
  }
  __syncthreads();
  int excl = iv - tsum + wred[wid];
  offs[base4]     = excl;
  offs[base4 + 1] = excl + c0;
  offs[base4 + 2] = excl + c0 + c1;
  offs[base4 + 3] = excl + c0 + c1 + c2;
  __syncthreads();
  for (int idx = tid; idx <= maxd; idx += 1024) levs_g[b * LSP + idx] = offs[idx];
  if (tid == 0) {
    levs_g[b * LSP + maxd + 1] = 4096;
    levs_g[b * LSP + 4098] = maxd + 1;
  }
  __syncthreads();   // levs_g copy must finish reading offs before scatter mutates it
  for (int k = 0; k < 4; ++k) {
    int v2 = tid + k * 1024;
    int pos = atomicAdd(&offs[dep[v2]], 1);
    int c = v2 & 63, r = v2 >> 6;
    unsigned msk = 0;
    if (r > 0  && par[v2 - 64] == v2) msk |= 1;
    if (c > 0  && par[v2 - 1]  == v2) msk |= 2;
    if (c < 63 && par[v2 + 1]  == v2) msk |= 4;
    if (r < 63 && par[v2 + 64] == v2) msk |= 8;
    topo_g[b * 4096 + pos] =
        (unsigned)v2 | (msk << 12) | ((unsigned)par[v2] << 16);
  }
}

// ---------------- scan: 72KB LDS, scatter up, level-serial (at DS-latency floor) ----------------
__global__ __launch_bounds__(64) void scan_kernel(
    float* __restrict__ buft, const float* __restrict__ ewt,
    const unsigned int* __restrict__ topo_g, const int* __restrict__ levs_g) {
  __shared__ float acc[16384];           // [node*4 + ch], 64 KB
  __shared__ unsigned short lvs[4104];   // 8 KB
  int bid = blockIdx.x;
  int b = bid >> 6, cg = bid & 63;
  int lane = threadIdx.x;
  int ch = lane & 3, slot = lane >> 2;
  int nlev = levs_g[b * LSP + 4098];
  size_t fbase = (size_t)(b * 64 + cg) * 16384;
  const float4* bt4 = reinterpret_cast<const float4*>(buft + fbase);
  const float*  ewf = ewt + fbase;
  const float4* et4 = reinterpret_cast<const float4*>(ewf);
  const unsigned int* tp = topo_g + b * 4096;
  float4* acc4 = reinterpret_cast<float4*>(acc);
  float wsum = 0.f;
  for (int n = lane; n < 4096; n += 64) {
    acc4[n] = bt4[n];
    float4 ev = et4[n];
    wsum += ev.x + ev.y + ev.z + ev.w;
  }
  asm volatile("" :: "v"(wsum));         // keep L2-warming reads live
  for (int i = lane; i <= nlev; i += 64) lvs[i] = (unsigned short)levs_g[b * LSP + i];
  __syncthreads();
  // ---- UP ----
  if (nlev > 1) {
    int lev0 = nlev - 1;
    int jA = lvs[lev0] + slot, eA = lvs[lev0 + 1];
    unsigned tA = tp[jA < 4096 ? jA : 4095];
    float elA = ewf[(tA & 4095) * 4 + ch];
    int jB = 0, eB = 0; unsigned tB = 0; float elB = 0.f;
    if (lev0 - 1 >= 1) {
      jB = lvs[lev0 - 1] + slot; eB = lvs[lev0];
      tB = tp[jB < 4096 ? jB : 4095];
      elB = ewf[(tB & 4095) * 4 + ch];
    }
    int jC = 0, eC = 0; unsigned tC = 0;
    if (lev0 - 2 >= 1) {
      jC = lvs[lev0 - 2] + slot; eC = lvs[lev0 - 1];
      tC = tp[jC < 4096 ? jC : 4095];
    }
    for (int lev = lev0; lev >= 1; --lev) {
      float elC = 0.f;
      if (lev - 2 >= 1) elC = ewf[(tC & 4095) * 4 + ch];
      int jD = 0, eD = 0; unsigned tD = 0;
      if (lev - 3 >= 1) {
        jD = lvs[lev - 3] + slot; eD = lvs[lev - 2];
        tD = tp[jD < 4096 ? jD : 4095];
      }
      if (jA < eA) {
        int vA = tA & 4095, pA = (tA >> 16) & 4095;
        float a = acc[vA * 4 + ch];
        atomicAdd(&acc[pA * 4 + ch], elA * a);
        for (int j = jA + 16; j < eA; j += 16) {
          unsigned t = tp[j];
          int v = t & 4095, p = (t >> 16) & 4095;
          float e = ewf[v * 4 + ch];
          float av = acc[v * 4 + ch];
          atomicAdd(&acc[p * 4 + ch], e * av);
        }
      }
      __builtin_amdgcn_wave_barrier();
      jA = jB; eA = eB; tA = tB; elA = elB;
      jB = jC; eB = eC; tB = tC; elB = elC;
      jC = jD; eC = eD; tC = tD;
    }
  }
  __builtin_amdgcn_wave_barrier();
  // ---- DOWN ----
  if (nlev > 1) {
    int jA = lvs[1] + slot, eA = lvs[2];
    unsigned tA = tp[jA < 4096 ? jA : 4095];
    float elA = ewf[(tA & 4095) * 4 + ch];
    int jB = 0, eB = 0; unsigned tB = 0; float elB = 0.f;
    if (2 < nlev) {
      jB = lvs[2] + slot; eB = lvs[3];
      tB = tp[jB < 4096 ? jB : 4095];
      elB = ewf[(tB & 4095) * 4 + ch];
    }
    int jC = 0, eC = 0; unsigned tC = 0;
    if (3 < nlev) {
      jC = lvs[3] + slot; eC = lvs[4];
      tC = tp[jC < 4096 ? jC : 4095];
    }
    for (int lev = 1; lev < nlev; ++lev) {
      float elC = 0.f;
      if (lev + 2 < nlev) elC = ewf[(tC & 4095) * 4 + ch];
      int jD = 0, eD = 0; unsigned tD = 0;
      if (lev + 3 < nlev) {
        jD = lvs[lev + 3] + slot; eD = lvs[lev + 4];
        tD = tp[jD < 4096 ? jD : 4095];
      }
      if (jA < eA) {
        int vA = tA & 4095, pA = (tA >> 16) & 4095;
        float uv = acc[vA * 4 + ch];
        float pb = acc[pA * 4 + ch];
        acc[vA * 4 + ch] = uv + elA * (pb - elA * uv);
        for (int j = jA + 16; j < eA; j += 16) {
          unsigned t = tp[j];
          int v = t & 4095, p = (t >> 16) & 4095;
          float e = ewf[v * 4 + ch];
          float uvv = acc[v * 4 + ch];
          float pbv = acc[p * 4 + ch];
          acc[v * 4 + ch] = uvv + e * (pbv - e * uvv);
        }
      }
      __builtin_amdgcn_wave_barrier();
      jA = jB; eA = eB; tA = tB; elA = elB;
      jB = jC; eB = eC; tB = tC; elB = elC;
      jC = jD; eC = eD; tC = tD;
    }
  }
  __syncthreads();
  float4* bw4 = reinterpret_cast<float4*>(buft + fbase);
  for (int n = lane; n < 4096; n += 64) bw4[n] = acc4[n];
}

// ---------------- post-scan v2: wave-per-pixel, barrier-free ----------------
// wave w of block handles pixel m = blockIdx*4 + w; lane holds channels 4*lane..4*lane+3.
__global__ __launch_bounds__(256) void post_kernel(
    const float* __restrict__ buft, const float* __restrict__ Cs,
    const float* __restrict__ xs, const float* __restrict__ ds,
    const float* __restrict__ hng, const float* __restrict__ hnb,
    const float* __restrict__ ong, const float* __restrict__ onb,
    float* __restrict__ zya) {
  int w = threadIdx.x >> 6, lane = threadIdx.x & 63;
  int m = blockIdx.x * 4 + w;
  int b = m >> 12, l = m & (LB - 1);
  float4 fo = *reinterpret_cast<const float4*>(
      buft + ((size_t)(b * 64 + lane) * 4096 + l) * 4);
  float mu = warp_sum(fo.x + fo.y + fo.z + fo.w) * (1.f / 256.f);
  float4 dv = make_float4(fo.x - mu, fo.y - mu, fo.z - mu, fo.w - mu);
  float var = warp_sum(dv.x * dv.x + dv.y * dv.y + dv.z * dv.z + dv.w * dv.w) * (1.f / 256.f);
  float rs = 1.0f / sqrtf(var + 1e-5f);
  float4 hg = reinterpret_cast<const float4*>(hng)[lane];
  float4 hb = reinterpret_cast<const float4*>(hnb)[lane];
  float csv = Cs[m];
  float4 dsv4 = reinterpret_cast<const float4*>(ds)[lane];
  float4 xv = reinterpret_cast<const float4*>(xs + (size_t)m * 256)[lane];
  float y0 = (dv.x * rs * hg.x + hb.x) * csv + dsv4.x * xv.x;
  float y1 = (dv.y * rs * hg.y + hb.y) * csv + dsv4.y * xv.y;
  float y2_ = (dv.z * rs * hg.z + hb.z) * csv + dsv4.z * xv.z;
  float y3 = (dv.w * rs * hg.w + hb.w) * csv + dsv4.w * xv.w;
  float mu2 = warp_sum(y0 + y1 + y2_ + y3) * (1.f / 256.f);
  float d0 = y0 - mu2, d1 = y1 - mu2, d2 = y2_ - mu2, d3 = y3 - mu2;
  float var2 = warp_sum(d0 * d0 + d1 * d1 + d2 * d2 + d3 * d3) * (1.f / 256.f);
  float rs2 = 1.0f / sqrtf(var2 + 1e-5f);
  float4 og = reinterpret_cast<const float4*>(ong)[lane];
  float4 ob = reinterpret_cast<const float4*>(onb)[lane];
  float4* zp = reinterpret_cast<float4*>(zya + (size_t)m * 256) + lane;
  float4 zv = *zp;
  zv.x = (d0 * rs2 * og.x + ob.x) * zv.x;
  zv.y = (d1 * rs2 * og.y + ob.y) * zv.y;
  zv.z = (d2 * rs2 * og.z + ob.z) * zv.z;
  zv.w = (d3 * rs2 * og.w + ob.w) * zv.w;
  *zp = zv;
}

// ---------------- launcher ----------------
extern "C" void kernel_launch(void* const* d_in, const int* in_sizes, int n_in,
                              void* d_out, int out_size, void* d_ws, size_t ws_size,
                              hipStream_t stream) {
  (void)in_sizes; (void)n_in; (void)out_size; (void)ws_size;
  const float* x      = (const float*)d_in[0];
  const float* ln1g   = (const float*)d_in[1];
  const float* ln1b   = (const float*)d_in[2];
  const float* ln2g   = (const float*)d_in[3];
  const float* ln2b   = (const float*)d_in[4];
  const float* w_in   = (const float*)d_in[5];
  const float* conv_w = (const float*)d_in[6];
  const float* xw     = (const float*)d_in[7];
  const float* dtw    = (const float*)d_in[8];
  const float* dtb    = (const float*)d_in[9];
  const float* alogs  = (const float*)d_in[10];
  const float* dsv    = (const float*)d_in[11];
  const float* hng    = (const float*)d_in[12];
  const float* hnb    = (const float*)d_in[13];
  const float* ong    = (const float*)d_in[14];
  const float* onb    = (const float*)d_in[15];
  const float* w_out  = (const float*)d_in[16];
  const float* mw1    = (const float*)d_in[17];
  const float* mb1    = (const float*)d_in[18];
  const float* mw2    = (const float*)d_in[19];
  const float* mb2    = (const float*)d_in[20];

  char* ws = (char*)d_ws;
  float* x1   = (float*)(ws + 0);            // 16MB
  float* z    = (float*)(ws + 16777216);     // 33.5MB (z, later ya in-place)
  float* xcp  = (float*)(ws + 50331648);     // 33.5MB
  float* xs   = (float*)(ws + 83886080);     // 33.5MB
  float* dAt  = (float*)(ws + 117440512);    // 33.5MB transposed deltaA
  float* featt= (float*)(ws + 150994944);    // 33.5MB transposed feat -> scan buf
  float* Cs   = (float*)(ws + 184549376);
  float* ssq  = (float*)(ws + 184680448);
  float* wr   = (float*)(ws + 184811520);
  float* wd   = (float*)(ws + 184942592);
  unsigned int* topo32 = (unsigned int*)(ws + 185073664);   // 128KB
  int*   levs = (int*)(ws + 185335808);
  float* midg = xs;      // 67MB spans xs+dAt (both dead by then)

  gemm128ln_kernel<1><<<dim3(4, 256), 256, 0, stream>>>(x, w_in, xcp, z, nullptr,
                                                        ln1g, ln1b, MROWS, 512, 128);
  convfeat_kernel<<<MROWS, 256, 0, stream>>>(xcp, conv_w, xw, dtw, dtb, alogs,
                                             xs, dAt, featt, Cs, ssq);
  gridw_kernel<<<MROWS, 256, 0, stream>>>(xs, ssq, wr, wd);
  mst_kernel<<<NB, 1024, 0, stream>>>(wr, wd, topo32, levs);
  scan_kernel<<<512, 64, 0, stream>>>(featt, dAt, topo32, levs);
  post_kernel<<<MROWS / 4, 256, 0, stream>>>(featt, Cs, xs, dsv, hng, hnb, ong, onb, z);
  gemm_kernel<2><<<dim3(2, 512), 256, 0, stream>>>(z, w_out, x1, nullptr, nullptr, x,
                                                   MROWS, 128, 256);
  gemm128ln_kernel<3><<<dim3(4, 256), 256, 0, stream>>>(x1, mw1, midg, nullptr, mb1,
                                                        ln2g, ln2b, MROWS, 512, 128);
  gemm_kernel<4><<<dim3(2, 512), 256, 0, stream>>>(midg, mw2, (float*)d_out, nullptr,
                                                   mb2, x1, MROWS, 128, 512);
}

// Round 16
// 782.255 us; speedup vs baseline: 1.0839x; 1.0655x over previous
//
#include <hip/hip_runtime.h>
#include <hip/hip_bf16.h>
#include <cstdint>

#define BIGF 1e30f
constexpr int LB   = 4096;           // L = H*W
constexpr int NB   = 8;              // batch
constexpr int MROWS = NB * LB;       // 32768 pixel rows
constexpr int LSP  = 4104;           // level-start stride per batch

// ---------------- helpers ----------------
__device__ __forceinline__ float warp_sum(float v) {
#pragma unroll
  for (int off = 32; off; off >>= 1) v += __shfl_xor(v, off);
  return v;
}

// ---------------- f32 GEMM 64x64 tile (EPI 2: +addsrc, EPI 4: +bias+addsrc) ----------------
template<int EPI>
__global__ __launch_bounds__(256) void gemm_kernel(
    const float* __restrict__ A, const float* __restrict__ W,
    float* __restrict__ C, float* __restrict__ C2,
    const float* __restrict__ bias, const float* __restrict__ addsrc,
    int M, int N, int K) {
  __shared__ float As[32][68];
  __shared__ float Bs[32][68];
  int t = threadIdx.x;
  int tx = t & 15, ty = t >> 4;
  int bm = blockIdx.y * 64, bn = blockIdx.x * 64;
  float acc[4][4] = {};
  for (int k0 = 0; k0 < K; k0 += 32) {
#pragma unroll
    for (int hh = 0; hh < 2; ++hh) {
      int q = t + hh * 256;
      int r = q >> 3, kc = q & 7;
      float4 a4 = reinterpret_cast<const float4*>(A + (size_t)(bm + r) * K + k0)[kc];
      float4 b4 = reinterpret_cast<const float4*>(W + (size_t)(bn + r) * K + k0)[kc];
      As[kc * 4 + 0][r] = a4.x; As[kc * 4 + 1][r] = a4.y;
      As[kc * 4 + 2][r] = a4.z; As[kc * 4 + 3][r] = a4.w;
      Bs[kc * 4 + 0][r] = b4.x; Bs[kc * 4 + 1][r] = b4.y;
      Bs[kc * 4 + 2][r] = b4.z; Bs[kc * 4 + 3][r] = b4.w;
    }
    __syncthreads();
#pragma unroll
    for (int kk = 0; kk < 32; ++kk) {
      float4 av = *reinterpret_cast<const float4*>(&As[kk][ty * 4]);
      float4 bv = *reinterpret_cast<const float4*>(&Bs[kk][tx * 4]);
      float aa[4] = {av.x, av.y, av.z, av.w};
      float bbv[4] = {bv.x, bv.y, bv.z, bv.w};
#pragma unroll
      for (int i = 0; i < 4; ++i)
#pragma unroll
        for (int j = 0; j < 4; ++j) acc[i][j] += aa[i] * bbv[j];
    }
    __syncthreads();
  }
#pragma unroll
  for (int i = 0; i < 4; ++i) {
    int m = bm + ty * 4 + i;
#pragma unroll
    for (int j = 0; j < 4; ++j) {
      int n = bn + tx * 4 + j;
      float v = acc[i][j];
      if (EPI == 2) {
        C[(size_t)m * N + n] = v + addsrc[(size_t)m * N + n];
      } else if (EPI == 4) {
        C[(size_t)m * N + n] = v + bias[n] + addsrc[(size_t)m * N + n];
      }
    }
  }
}

// ------- f32 GEMM 128x128 tile with FUSED LayerNorm on A (EPI 1: split+silu, EPI 3: +bias+gelu) -------
template<int EPI>
__global__ __launch_bounds__(256) void gemm128ln_kernel(
    const float* __restrict__ A, const float* __restrict__ W,
    float* __restrict__ C, float* __restrict__ C2,
    const float* __restrict__ bias, const float* __restrict__ lng,
    const float* __restrict__ lnb, int M, int N, int K) {
  __shared__ float As[32][132];
  __shared__ float Bs[32][132];
  __shared__ float mu_s[128], rs_s[128], g_s[128], b_s[128];
  int t = threadIdx.x;
  int tx = t & 15, ty = t >> 4;
  int bm = blockIdx.y * 128, bn = blockIdx.x * 128;
  {
    int r = t >> 1, hf = t & 1;
    const float4* row = reinterpret_cast<const float4*>(A + (size_t)(bm + r) * K + hf * 64);
    float s = 0.f;
#pragma unroll
    for (int i = 0; i < 16; ++i) { float4 v = row[i]; s += v.x + v.y + v.z + v.w; }
    s += __shfl_xor(s, 1);
    float mu = s * (1.0f / 128.0f);
    float sq = 0.f;
#pragma unroll
    for (int i = 0; i < 16; ++i) {
      float4 v = row[i];
      float d0 = v.x - mu, d1 = v.y - mu, d2 = v.z - mu, d3 = v.w - mu;
      sq += d0 * d0 + d1 * d1 + d2 * d2 + d3 * d3;
    }
    sq += __shfl_xor(sq, 1);
    if (hf == 0) {
      mu_s[r] = mu;
      rs_s[r] = 1.0f / sqrtf(sq * (1.0f / 128.0f) + 1e-6f);
    }
    if (t < 128) { g_s[t] = lng[t]; b_s[t] = lnb[t]; }
  }
  __syncthreads();
  float acc[8][8] = {};
  for (int k0 = 0; k0 < K; k0 += 32) {
#pragma unroll
    for (int hh = 0; hh < 4; ++hh) {
      int q = t + hh * 256;
      int r = q >> 3, kc = q & 7;
      float4 a4 = *reinterpret_cast<const float4*>(A + (size_t)(bm + r) * K + k0 + kc * 4);
      float4 b4 = *reinterpret_cast<const float4*>(W + (size_t)(bn + r) * K + k0 + kc * 4);
      float mu = mu_s[r], rs = rs_s[r];
      int c0 = k0 + kc * 4;
      As[kc * 4 + 0][r] = (a4.x - mu) * rs * g_s[c0]     + b_s[c0];
      As[kc * 4 + 1][r] = (a4.y - mu) * rs * g_s[c0 + 1] + b_s[c0 + 1];
      As[kc * 4 + 2][r] = (a4.z - mu) * rs * g_s[c0 + 2] + b_s[c0 + 2];
      As[kc * 4 + 3][r] = (a4.w - mu) * rs * g_s[c0 + 3] + b_s[c0 + 3];
      Bs[kc * 4 + 0][r] = b4.x; Bs[kc * 4 + 1][r] = b4.y;
      Bs[kc * 4 + 2][r] = b4.z; Bs[kc * 4 + 3][r] = b4.w;
    }
    __syncthreads();
#pragma unroll
    for (int kk = 0; kk < 32; ++kk) {
      float4 a0 = *reinterpret_cast<const float4*>(&As[kk][ty * 4]);
      float4 a1 = *reinterpret_cast<const float4*>(&As[kk][64 + ty * 4]);
      float4 b0 = *reinterpret_cast<const float4*>(&Bs[kk][tx * 4]);
      float4 b1 = *reinterpret_cast<const float4*>(&Bs[kk][64 + tx * 4]);
      float aa[8] = {a0.x, a0.y, a0.z, a0.w, a1.x, a1.y, a1.z, a1.w};
      float bb2[8] = {b0.x, b0.y, b0.z, b0.w, b1.x, b1.y, b1.z, b1.w};
#pragma unroll
      for (int i = 0; i < 8; ++i)
#pragma unroll
        for (int j = 0; j < 8; ++j) acc[i][j] += aa[i] * bb2[j];
    }
    __syncthreads();
  }
#pragma unroll
  for (int i = 0; i < 8; ++i) {
    int m = bm + (i >> 2) * 64 + ty * 4 + (i & 3);
#pragma unroll
    for (int j = 0; j < 8; ++j) {
      int n = bn + (j >> 2) * 64 + tx * 4 + (j & 3);
      float v = acc[i][j];
      if (EPI == 1) {
        if (n < 256) C[(size_t)m * 256 + n] = v;
        else C2[(size_t)m * 256 + (n - 256)] = v / (1.0f + __expf(-v));
      } else if (EPI == 3) {
        float u = v + bias[n];
        float xg = 1.5957691216057308f * (u + 0.044715f * u * u * u);
        C[(size_t)m * N + n] = u / (1.0f + __expf(-xg));
      }
    }
  }
}

// ---------------- convfeat v2: wave-per-pixel, float4 everything ----------------
// feat/dA written TRANSPOSED: [(b*64+lane)*4096 + l] float4
__global__ __launch_bounds__(256) void convfeat_kernel(
    const float* __restrict__ xcpre, const float* __restrict__ cw,
    const float* __restrict__ xw, const float* __restrict__ dtw,
    const float* __restrict__ dtb, const float* __restrict__ alogs,
    float* __restrict__ xs, float* __restrict__ dAt, float* __restrict__ featt,
    float* __restrict__ Cs, float* __restrict__ ssq) {
  __shared__ float cws[9 * 256];        // transposed [k][d]
  int t = threadIdx.x;
#pragma unroll
  for (int k = 0; k < 9; ++k) cws[k * 256 + t] = cw[t * 9 + k];
  __syncthreads();
  int w = t >> 6, lane = t & 63;
  int m = blockIdx.x * 4 + w;
  int l = m & (LB - 1), b = m >> 12;
  int r = l >> 6, c = l & 63;
  const float4* xc4 = reinterpret_cast<const float4*>(xcpre);
  float ax = 0.f, ay = 0.f, az = 0.f, aw = 0.f;
#pragma unroll
  for (int ky = 0; ky < 3; ++ky) {
    int rr = r + ky - 1;
    if (rr < 0 || rr > 63) continue;
#pragma unroll
    for (int kx = 0; kx < 3; ++kx) {
      int cc = c + kx - 1;
      if (cc < 0 || cc > 63) continue;
      int ml = (b << 12) + (rr << 6) + cc;
      float4 v = xc4[(size_t)ml * 64 + lane];
      float4 wv = *reinterpret_cast<const float4*>(&cws[(ky * 3 + kx) * 256 + lane * 4]);
      ax += v.x * wv.x; ay += v.y * wv.y; az += v.z * wv.z; aw += v.w * wv.w;
    }
  }
  float4 xv;
  xv.x = ax / (1.0f + __expf(-ax));
  xv.y = ay / (1.0f + __expf(-ay));
  xv.z = az / (1.0f + __expf(-az));
  xv.w = aw / (1.0f + __expf(-aw));
  reinterpret_cast<float4*>(xs)[(size_t)m * 64 + lane] = xv;
  // 11 reductions: p[0..9] = <xv, xw_i>, p[10] = <xv,xv>
  float red[11];
#pragma unroll
  for (int i = 0; i < 10; ++i) {
    float4 wv = reinterpret_cast<const float4*>(xw)[i * 64 + lane];
    red[i] = warp_sum(xv.x * wv.x + xv.y * wv.y + xv.z * wv.z + xv.w * wv.w);
  }
  red[10] = warp_sum(xv.x * xv.x + xv.y * xv.y + xv.z * xv.z + xv.w * xv.w);
  // dts + softplus + dA + feat, 4 channels per lane
  float4 dtb4 = reinterpret_cast<const float4*>(dtb)[lane];
  float4 al4  = reinterpret_cast<const float4*>(alogs)[lane];
  float xdt[4] = {dtb4.x, dtb4.y, dtb4.z, dtb4.w};
#pragma unroll
  for (int j = 0; j < 4; ++j) {
    int d = lane * 4 + j;
    float4 w0 = *reinterpret_cast<const float4*>(dtw + d * 8);
    float4 w1 = *reinterpret_cast<const float4*>(dtw + d * 8 + 4);
    xdt[j] += red[0] * w0.x + red[1] * w0.y + red[2] * w0.z + red[3] * w0.w
            + red[4] * w1.x + red[5] * w1.y + red[6] * w1.z + red[7] * w1.w;
  }
  float alv[4] = {al4.x, al4.y, al4.z, al4.w};
  float4 dA4, ft4;
  float* dAp = &dA4.x;
  float* ftp = &ft4.x;
#pragma unroll
  for (int j = 0; j < 4; ++j) {
    float sp = fmaxf(xdt[j], 0.f) + __logf(1.0f + __expf(-fabsf(xdt[j])));
    float As_ = -__expf(alv[j]);
    dAp[j] = __expf(sp * As_);
    float xvj = (j == 0) ? xv.x : (j == 1) ? xv.y : (j == 2) ? xv.z : xv.w;
    ftp[j] = sp * red[8] * xvj;
  }
  size_t tb = (size_t)(b * 64 + lane) * 4096 + l;
  reinterpret_cast<float4*>(dAt)[tb]   = dA4;
  reinterpret_cast<float4*>(featt)[tb] = ft4;
  if (lane == 0) { Cs[m] = red[9]; ssq[m] = red[10]; }
}

// ---------------- gridw v2: wave-per-pixel, float4, barrier-free ----------------
__global__ __launch_bounds__(256) void gridw_kernel(
    const float* __restrict__ xs, const float* __restrict__ ssq,
    float* __restrict__ wrg, float* __restrict__ wdg) {
  int w = threadIdx.x >> 6, lane = threadIdx.x & 63;
  int m = blockIdx.x * 4 + w;
  int l = m & (LB - 1);
  int r = l >> 6, c = l & 63;
  const float4* xs4 = reinterpret_cast<const float4*>(xs);
  float4 a = xs4[(size_t)m * 64 + lane];
  float4 br = (c < 63) ? xs4[(size_t)(m + 1) * 64 + lane] : make_float4(0, 0, 0, 0);
  float4 bd = (r < 63) ? xs4[(size_t)(m + 64) * 64 + lane] : make_float4(0, 0, 0, 0);
  float s1 = warp_sum(a.x * br.x + a.y * br.y + a.z * br.z + a.w * br.w);
  float s2 = warp_sum(a.x * bd.x + a.y * bd.y + a.z * bd.z + a.w * bd.w);
  if (lane == 0) {
    float na = sqrtf(ssq[m]);
    float wrv = BIGF, wdv = BIGF;
    if (c < 63) { float den = fmaxf(na * sqrtf(ssq[m + 1]), 1e-8f);  wrv = expf(-(s1 / den)); }
    if (r < 63) { float den = fmaxf(na * sqrtf(ssq[m + 64]), 1e-8f); wdv = expf(-(s2 / den)); }
    wrg[m] = wrv; wdg[m] = wdv;
  }
}

// ---------------- Boruvka MST + Euler-tour rooting (O(log V)) + levels ----------------
// Output: topo32[pos] = node | childmask<<12 | par<<16 ; levs_g per batch.
__global__ __launch_bounds__(1024) void mst_kernel(
    const float* __restrict__ wr_g, const float* __restrict__ wd_g,
    unsigned int* __restrict__ topo_g, int* __restrict__ levs_g) {
  __shared__ int pool[24592];          // 98.4 KB, phase-overlaid
  __shared__ unsigned char flagR[4096];
  __shared__ unsigned char flagD[4096];
  __shared__ int ncomp_s;
  __shared__ int wred[16];
  int b = blockIdx.x, tid = threadIdx.x;
  float* wrs = (float*)pool;
  float* wds = (float*)(pool + 4096);
  int* comp = pool + 8192;
  int* lnk  = pool + 12288;
  unsigned int* bestw = (unsigned int*)(pool + 16384);
  int* beste = pool + 20480;
  const float* wrb = wr_g + b * 4096;
  const float* wdb = wd_g + b * 4096;
  for (int k = 0; k < 4; ++k) {
    int i = tid + k * 1024;
    wrs[i] = wrb[i]; wds[i] = wdb[i];
    comp[i] = i; flagR[i] = 0; flagD[i] = 0;
  }
  __syncthreads();
  for (int phase = 0; phase < 13; ++phase) {
    for (int k = 0; k < 4; ++k) {
      int c = tid + k * 1024;
      bestw[c] = 0xFFFFFFFFu; beste[c] = 0x7FFFFFFF; lnk[c] = c;
    }
    if (tid == 0) ncomp_s = 0;
    __syncthreads();
    for (int k = 0; k < 8; ++k) {
      int e = tid + k * 1024;
      int v = e & 4095;
      bool isR = e < 4096;
      int c = v & 63, r = v >> 6;
      bool valid = isR ? (c < 63) : (r < 63);
      if (valid) {
        int u = isR ? v + 1 : v + 64;
        int ca = comp[v], cb = comp[u];
        if (ca != cb) {
          unsigned wbits = __float_as_uint(isR ? wrs[v] : wds[v]);
          atomicMin(&bestw[ca], wbits);
          atomicMin(&bestw[cb], wbits);
        }
      }
    }
    __syncthreads();
    for (int k = 0; k < 8; ++k) {
      int e = tid + k * 1024;
      int v = e & 4095;
      bool isR = e < 4096;
      int c = v & 63, r = v >> 6;
      bool valid = isR ? (c < 63) : (r < 63);
      if (valid) {
        int u = isR ? v + 1 : v + 64;
        int ca = comp[v], cb = comp[u];
        if (ca != cb) {
          unsigned wbits = __float_as_uint(isR ? wrs[v] : wds[v]);
          if (wbits == bestw[ca]) atomicMin(&beste[ca], e);
          if (wbits == bestw[cb]) atomicMin(&beste[cb], e);
        }
      }
    }
    __syncthreads();
    for (int k = 0; k < 4; ++k) {
      int cc = tid + k * 1024;
      int e = beste[cc];
      if (e != 0x7FFFFFFF) {
        int v = e & 4095;
        bool isR = e < 4096;
        int u = isR ? v + 1 : v + 64;
        if (isR) flagR[v] = 1; else flagD[v] = 1;
        int ca = comp[v], cb = comp[u];
        lnk[cc] = (ca == cc) ? cb : ca;
      }
    }
    __syncthreads();
    for (int k = 0; k < 4; ++k) {
      int cc = tid + k * 1024;
      int l = lnk[cc];
      if (l != cc && lnk[l] == cc && cc < l) lnk[cc] = cc;
    }
    __syncthreads();
    // adaptive pointer jumping: comps <= 4096/2^phase -> depth <= that -> 12-phase iters suffice
    int iters = 12 - phase; if (iters < 3) iters = 3;
    for (int it = 0; it < iters; ++it) {
      for (int k = 0; k < 4; ++k) {
        int cc = tid + k * 1024;
        lnk[cc] = lnk[lnk[cc]];
      }
      __syncthreads();
    }
    for (int k = 0; k < 4; ++k) {
      int i = tid + k * 1024;
      comp[i] = lnk[comp[i]];
      if (comp[i] == i) atomicAdd(&ncomp_s, 1);
    }
    __syncthreads();
    if (ncomp_s <= 1) break;
    __syncthreads();
  }
  // ---- Euler tour ----
  unsigned short* nxt = (unsigned short*)pool;        // [16400]
  short*          dsv = (short*)(pool + 8200);        // [16400]
  int* par = pool + 16400;                            // [4096]
  int* dep = pool + 20496;                            // [4096]
  const int NIL = 16384;
  unsigned short rn[16];
  int rd[16];
  int validm = 0;
  for (int k = 0; k < 4; ++k) { int i = tid + k * 1024; par[i] = 0; dep[i] = 0; }
#pragma unroll
  for (int k = 0; k < 16; ++k) {
    int a = tid + k * 1024;
    int u = a >> 2, d = a & 3;
    int c = u & 63, r = u >> 6;
    int mu = 0;
    if (r > 0  && flagD[u - 64]) mu |= 1;
    if (c > 0  && flagR[u - 1])  mu |= 2;
    if (c < 63 && flagR[u])      mu |= 4;
    if (r < 63 && flagD[u])      mu |= 8;
    unsigned short nx = NIL; short dv = 0;
    if (mu & (1 << d)) {
      validm |= 1 << k;
      int v = u + ((d == 0) ? -64 : (d == 1) ? -1 : (d == 2) ? 1 : 64);
      int cv = v & 63, rv = v >> 6;
      int mv = 0;
      if (rv > 0  && flagD[v - 64]) mv |= 1;
      if (cv > 0  && flagR[v - 1])  mv |= 2;
      if (cv < 63 && flagR[v])      mv |= 4;
      if (rv < 63 && flagD[v])      mv |= 8;
      int din = 3 - d;
      int hi = mv >> (din + 1);
      int dn = hi ? (din + __ffs(hi)) : (__ffs(mv) - 1);
      int nxv = v * 4 + dn;
      int m0 = (flagR[0] ? 4 : 0) | (flagD[0] ? 8 : 0);
      int a0 = __ffs(m0) - 1;
      if (v == 0 && nxv == a0) nxv = NIL;
      nx = (unsigned short)nxv;
      dv = 1;
    }
    nxt[a] = nx; dsv[a] = dv;
    rn[k] = nx; rd[k] = dv;
  }
  if (tid == 0) { nxt[NIL] = NIL; dsv[NIL] = 0; }
  __syncthreads();
#pragma unroll 1
  for (int it = 0; it < 13; ++it) {
    unsigned short nn[16]; short nd[16];
#pragma unroll
    for (int k = 0; k < 16; ++k) { nn[k] = nxt[rn[k]]; nd[k] = dsv[rn[k]]; }
    __syncthreads();
#pragma unroll
    for (int k = 0; k < 16; ++k) {
      int a = tid + k * 1024;
      rd[k] += nd[k];
      rn[k] = nn[k];
      nxt[a] = rn[k]; dsv[a] = (short)rd[k];
    }
    __syncthreads();
  }
#pragma unroll
  for (int k = 0; k < 16; ++k) if (validm & (1 << k)) {
    int a = tid + k * 1024;
    int u = a >> 2, d = a & 3;
    int v = u + ((d == 0) ? -64 : (d == 1) ? -1 : (d == 2) ? 1 : 64);
    int rb = v * 4 + (3 - d);
    if (rd[k] > (int)dsv[rb]) par[v] = u;
  }
  __syncthreads();
#pragma unroll
  for (int k = 0; k < 16; ++k) {
    int a = tid + k * 1024;
    int u = a >> 2, d = a & 3;
    unsigned short nx = NIL; short dv = 0;
    if (validm & (1 << k)) {
      int v = u + ((d == 0) ? -64 : (d == 1) ? -1 : (d == 2) ? 1 : 64);
      int cv = v & 63, rv = v >> 6;
      int mv = 0;
      if (rv > 0  && flagD[v - 64]) mv |= 1;
      if (cv > 0  && flagR[v - 1])  mv |= 2;
      if (cv < 63 && flagR[v])      mv |= 4;
      if (rv < 63 && flagD[v])      mv |= 8;
      int din = 3 - d;
      int hi = mv >> (din + 1);
      int dn = hi ? (din + __ffs(hi)) : (__ffs(mv) - 1);
      int nxv = v * 4 + dn;
      int m0 = (flagR[0] ? 4 : 0) | (flagD[0] ? 8 : 0);
      int a0 = __ffs(m0) - 1;
      if (v == 0 && nxv == a0) nxv = NIL;
      nx = (unsigned short)nxv;
      dv = (par[v] == u) ? (short)1 : (short)-1;
    }
    nxt[a] = nx; dsv[a] = dv;
    rn[k] = nx; rd[k] = dv;
  }
  __syncthreads();
#pragma unroll 1
  for (int it = 0; it < 13; ++it) {
    unsigned short nn[16]; short nd[16];
#pragma unroll
    for (int k = 0; k < 16; ++k) { nn[k] = nxt[rn[k]]; nd[k] = dsv[rn[k]]; }
    __syncthreads();
#pragma unroll
    for (int k = 0; k < 16; ++k) {
      int a = tid + k * 1024;
      rd[k] += nd[k];
      rn[k] = nn[k];
      nxt[a] = rn[k]; dsv[a] = (short)rd[k];
    }
    __syncthreads();
  }
#pragma unroll
  for (int k = 0; k < 16; ++k) if (validm & (1 << k)) {
    int a = tid + k * 1024;
    int u = a >> 2, d = a & 3;
    int v = u + ((d == 0) ? -64 : (d == 1) ? -1 : (d == 2) ? 1 : 64);
    if (par[v] == u) dep[v] = 1 - rd[k];
  }
  __syncthreads();
  int md = 0;
  for (int k = 0; k < 4; ++k) md = max(md, dep[tid + k * 1024]);
#pragma unroll
  for (int off = 32; off; off >>= 1) md = max(md, __shfl_xor(md, off));
  if ((tid & 63) == 0) wred[tid >> 6] = md;
  __syncthreads();
  if (tid == 0) {
    int m = 0;
    for (int i = 0; i < 16; ++i) m = max(m, wred[i]);
    wred[0] = m;
  }
  __syncthreads();
  int maxd = wred[0];
  __syncthreads();
  int* cnt  = pool;
  int* offs = pool + 4096;
  for (int k = 0; k < 4; ++k) cnt[tid + k * 1024] = 0;
  __syncthreads();
  for (int k = 0; k < 4; ++k) atomicAdd(&cnt[dep[tid + k * 1024]], 1);
  __syncthreads();
  int base4 = tid * 4;
  int c0 = cnt[base4], c1 = cnt[base4 + 1], c2 = cnt[base4 + 2], c3 = cnt[base4 + 3];
  int tsum = c0 + c1 + c2 + c3;
  int lane = tid & 63, wid = tid >> 6;
  int iv = tsum;
  for (int off = 1; off < 64; off <<= 1) {
    int n = __shfl_up(iv, off);
    if (lane >= off) iv += n;
  }
  if (lane == 63) wred[wid] = iv;
  __syncthreads();
  if (tid == 0) {
    int acc = 0;
    for (int i = 0; i < 16; ++i) { int t = wred[i]; wred[i] = acc; acc += t; }
  }
  __syncthreads();
  int excl = iv - tsum + wred[wid];
  offs[base4]     = excl;
  offs[base4 + 1] = excl + c0;
  offs[base4 + 2] = excl + c0 + c1;
  offs[base4 + 3] = excl + c0 + c1 + c2;
  __syncthreads();
  for (int idx = tid; idx <= maxd; idx += 1024) levs_g[b * LSP + idx] = offs[idx];
  if (tid == 0) {
    levs_g[b * LSP + maxd + 1] = 4096;
    levs_g[b * LSP + 4098] = maxd + 1;
  }
  __syncthreads();   // levs_g copy must finish reading offs before scatter mutates it
  for (int k = 0; k < 4; ++k) {
    int v2 = tid + k * 1024;
    int pos = atomicAdd(&offs[dep[v2]], 1);
    int c = v2 & 63, r = v2 >> 6;
    unsigned msk = 0;
    if (r > 0  && par[v2 - 64] == v2) msk |= 1;
    if (c > 0  && par[v2 - 1]  == v2) msk |= 2;
    if (c < 63 && par[v2 + 1]  == v2) msk |= 4;
    if (r < 63 && par[v2 + 64] == v2) msk |= 8;
    topo_g[b * 4096 + pos] =
        (unsigned)v2 | (msk << 12) | ((unsigned)par[v2] << 16);
  }
}

// ---------------- scan: 72KB LDS, scatter up, level-serial (at DS-latency floor) ----------------
__global__ __launch_bounds__(64) void scan_kernel(
    float* __restrict__ buft, const float* __restrict__ ewt,
    const unsigned int* __restrict__ topo_g, const int* __restrict__ levs_g) {
  __shared__ float acc[16384];           // [node*4 + ch], 64 KB
  __shared__ unsigned short lvs[4104];   // 8 KB
  int bid = blockIdx.x;
  int b = bid >> 6, cg = bid & 63;
  int lane = threadIdx.x;
  int ch = lane & 3, slot = lane >> 2;
  int nlev = levs_g[b * LSP + 4098];
  size_t fbase = (size_t)(b * 64 + cg) * 16384;
  const float4* bt4 = reinterpret_cast<const float4*>(buft + fbase);
  const float*  ewf = ewt + fbase;
  const float4* et4 = reinterpret_cast<const float4*>(ewf);
  const unsigned int* tp = topo_g + b * 4096;
  float4* acc4 = reinterpret_cast<float4*>(acc);
  float wsum = 0.f;
  for (int n = lane; n < 4096; n += 64) {
    acc4[n] = bt4[n];
    float4 ev = et4[n];
    wsum += ev.x + ev.y + ev.z + ev.w;
  }
  asm volatile("" :: "v"(wsum));         // keep L2-warming reads live
  for (int i = lane; i <= nlev; i += 64) lvs[i] = (unsigned short)levs_g[b * LSP + i];
  __syncthreads();
  // ---- UP ----
  if (nlev > 1) {
    int lev0 = nlev - 1;
    int jA = lvs[lev0] + slot, eA = lvs[lev0 + 1];
    unsigned tA = tp[jA < 4096 ? jA : 4095];
    float elA = ewf[(tA & 4095) * 4 + ch];
    int jB = 0, eB = 0; unsigned tB = 0; float elB = 0.f;
    if (lev0 - 1 >= 1) {
      jB = lvs[lev0 - 1] + slot; eB = lvs[lev0];
      tB = tp[jB < 4096 ? jB : 4095];
      elB = ewf[(tB & 4095) * 4 + ch];
    }
    int jC = 0, eC = 0; unsigned tC = 0;
    if (lev0 - 2 >= 1) {
      jC = lvs[lev0 - 2] + slot; eC = lvs[lev0 - 1];
      tC = tp[jC < 4096 ? jC : 4095];
    }
    for (int lev = lev0; lev >= 1; --lev) {
      float elC = 0.f;
      if (lev - 2 >= 1) elC = ewf[(tC & 4095) * 4 + ch];
      int jD = 0, eD = 0; unsigned tD = 0;
      if (lev - 3 >= 1) {
        jD = lvs[lev - 3] + slot; eD = lvs[lev - 2];
        tD = tp[jD < 4096 ? jD : 4095];
      }
      if (jA < eA) {
        int vA = tA & 4095, pA = (tA >> 16) & 4095;
        float a = acc[vA * 4 + ch];
        atomicAdd(&acc[pA * 4 + ch], elA * a);
        for (int j = jA + 16; j < eA; j += 16) {
          unsigned t = tp[j];
          int v = t & 4095, p = (t >> 16) & 4095;
          float e = ewf[v * 4 + ch];
          float av = acc[v * 4 + ch];
          atomicAdd(&acc[p * 4 + ch], e * av);
        }
      }
      __builtin_amdgcn_wave_barrier();
      jA = jB; eA = eB; tA = tB; elA = elB;
      jB = jC; eB = eC; tB = tC; elB = elC;
      jC = jD; eC = eD; tC = tD;
    }
  }
  __builtin_amdgcn_wave_barrier();
  // ---- DOWN ----
  if (nlev > 1) {
    int jA = lvs[1] + slot, eA = lvs[2];
    unsigned tA = tp[jA < 4096 ? jA : 4095];
    float elA = ewf[(tA & 4095) * 4 + ch];
    int jB = 0, eB = 0; unsigned tB = 0; float elB = 0.f;
    if (2 < nlev) {
      jB = lvs[2] + slot; eB = lvs[3];
      tB = tp[jB < 4096 ? jB : 4095];
      elB = ewf[(tB & 4095) * 4 + ch];
    }
    int jC = 0, eC = 0; unsigned tC = 0;
    if (3 < nlev) {
      jC = lvs[3] + slot; eC = lvs[4];
      tC = tp[jC < 4096 ? jC : 4095];
    }
    for (int lev = 1; lev < nlev; ++lev) {
      float elC = 0.f;
      if (lev + 2 < nlev) elC = ewf[(tC & 4095) * 4 + ch];
      int jD = 0, eD = 0; unsigned tD = 0;
      if (lev + 3 < nlev) {
        jD = lvs[lev + 3] + slot; eD = lvs[lev + 4];
        tD = tp[jD < 4096 ? jD : 4095];
      }
      if (jA < eA) {
        int vA = tA & 4095, pA = (tA >> 16) & 4095;
        float uv = acc[vA * 4 + ch];
        float pb = acc[pA * 4 + ch];
        acc[vA * 4 + ch] = uv + elA * (pb - elA * uv);
        for (int j = jA + 16; j < eA; j += 16) {
          unsigned t = tp[j];
          int v = t & 4095, p = (t >> 16) & 4095;
          float e = ewf[v * 4 + ch];
          float uvv = acc[v * 4 + ch];
          float pbv = acc[p * 4 + ch];
          acc[v * 4 + ch] = uvv + e * (pbv - e * uvv);
        }
      }
      __builtin_amdgcn_wave_barrier();
      jA = jB; eA = eB; tA = tB; elA = elB;
      jB = jC; eB = eC; tB = tC; elB = elC;
      jC = jD; eC = eD; tC = tD;
    }
  }
  __syncthreads();
  float4* bw4 = reinterpret_cast<float4*>(buft + fbase);
  for (int n = lane; n < 4096; n += 64) bw4[n] = acc4[n];
}

// ---------------- post-scan v2: wave-per-pixel, barrier-free ----------------
__global__ __launch_bounds__(256) void post_kernel(
    const float* __restrict__ buft, const float* __restrict__ Cs,
    const float* __restrict__ xs, const float* __restrict__ ds,
    const float* __restrict__ hng, const float* __restrict__ hnb,
    const float* __restrict__ ong, const float* __restrict__ onb,
    float* __restrict__ zya) {
  int w = threadIdx.x >> 6, lane = threadIdx.x & 63;
  int m = blockIdx.x * 4 + w;
  int b = m >> 12, l = m & (LB - 1);
  float4 fo = *reinterpret_cast<const float4*>(
      buft + ((size_t)(b * 64 + lane) * 4096 + l) * 4);
  float mu = warp_sum(fo.x + fo.y + fo.z + fo.w) * (1.f / 256.f);
  float4 dv = make_float4(fo.x - mu, fo.y - mu, fo.z - mu, fo.w - mu);
  float var = warp_sum(dv.x * dv.x + dv.y * dv.y + dv.z * dv.z + dv.w * dv.w) * (1.f / 256.f);
  float rs = 1.0f / sqrtf(var + 1e-5f);
  float4 hg = reinterpret_cast<const float4*>(hng)[lane];
  float4 hb = reinterpret_cast<const float4*>(hnb)[lane];
  float csv = Cs[m];
  float4 dsv4 = reinterpret_cast<const float4*>(ds)[lane];
  float4 xv = reinterpret_cast<const float4*>(xs + (size_t)m * 256)[lane];
  float y0 = (dv.x * rs * hg.x + hb.x) * csv + dsv4.x * xv.x;
  float y1 = (dv.y * rs * hg.y + hb.y) * csv + dsv4.y * xv.y;
  float y2_ = (dv.z * rs * hg.z + hb.z) * csv + dsv4.z * xv.z;
  float y3 = (dv.w * rs * hg.w + hb.w) * csv + dsv4.w * xv.w;
  float mu2 = warp_sum(y0 + y1 + y2_ + y3) * (1.f / 256.f);
  float d0 = y0 - mu2, d1 = y1 - mu2, d2 = y2_ - mu2, d3 = y3 - mu2;
  float var2 = warp_sum(d0 * d0 + d1 * d1 + d2 * d2 + d3 * d3) * (1.f / 256.f);
  float rs2 = 1.0f / sqrtf(var2 + 1e-5f);
  float4 og = reinterpret_cast<const float4*>(ong)[lane];
  float4 ob = reinterpret_cast<const float4*>(onb)[lane];
  float4* zp = reinterpret_cast<float4*>(zya + (size_t)m * 256) + lane;
  float4 zv = *zp;
  zv.x = (d0 * rs2 * og.x + ob.x) * zv.x;
  zv.y = (d1 * rs2 * og.y + ob.y) * zv.y;
  zv.z = (d2 * rs2 * og.z + ob.z) * zv.z;
  zv.w = (d3 * rs2 * og.w + ob.w) * zv.w;
  *zp = zv;
}

// ---------------- launcher ----------------
extern "C" void kernel_launch(void* const* d_in, const int* in_sizes, int n_in,
                              void* d_out, int out_size, void* d_ws, size_t ws_size,
                              hipStream_t stream) {
  (void)in_sizes; (void)n_in; (void)out_size; (void)ws_size;
  const float* x      = (const float*)d_in[0];
  const float* ln1g   = (const float*)d_in[1];
  const float* ln1b   = (const float*)d_in[2];
  const float* ln2g   = (const float*)d_in[3];
  const float* ln2b   = (const float*)d_in[4];
  const float* w_in   = (const float*)d_in[5];
  const float* conv_w = (const float*)d_in[6];
  const float* xw     = (const float*)d_in[7];
  const float* dtw    = (const float*)d_in[8];
  const float* dtb    = (const float*)d_in[9];
  const float* alogs  = (const float*)d_in[10];
  const float* dsv    = (const float*)d_in[11];
  const float* hng    = (const float*)d_in[12];
  const float* hnb    = (const float*)d_in[13];
  const float* ong    = (const float*)d_in[14];
  const float* onb    = (const float*)d_in[15];
  const float* w_out  = (const float*)d_in[16];
  const float* mw1    = (const float*)d_in[17];
  const float* mb1    = (const float*)d_in[18];
  const float* mw2    = (const float*)d_in[19];
  const float* mb2    = (const float*)d_in[20];

  char* ws = (char*)d_ws;
  float* x1   = (float*)(ws + 0);            // 16MB
  float* z    = (float*)(ws + 16777216);     // 33.5MB (z, later ya in-place)
  float* xcp  = (float*)(ws + 50331648);     // 33.5MB
  float* xs   = (float*)(ws + 83886080);     // 33.5MB
  float* dAt  = (float*)(ws + 117440512);    // 33.5MB transposed deltaA
  float* featt= (float*)(ws + 150994944);    // 33.5MB transposed feat -> scan buf
  float* Cs   = (float*)(ws + 184549376);
  float* ssq  = (float*)(ws + 184680448);
  float* wr   = (float*)(ws + 184811520);
  float* wd   = (float*)(ws + 184942592);
  unsigned int* topo32 = (unsigned int*)(ws + 185073664);   // 128KB
  int*   levs = (int*)(ws + 185335808);
  float* midg = xs;      // 67MB spans xs+dAt (both dead by then)

  gemm128ln_kernel<1><<<dim3(4, 256), 256, 0, stream>>>(x, w_in, xcp, z, nullptr,
                                                        ln1g, ln1b, MROWS, 512, 128);
  convfeat_kernel<<<MROWS / 4, 256, 0, stream>>>(xcp, conv_w, xw, dtw, dtb, alogs,
                                                 xs, dAt, featt, Cs, ssq);
  gridw_kernel<<<MROWS / 4, 256, 0, stream>>>(xs, ssq, wr, wd);
  mst_kernel<<<NB, 1024, 0, stream>>>(wr, wd, topo32, levs);
  scan_kernel<<<512, 64, 0, stream>>>(featt, dAt, topo32, levs);
  post_kernel<<<MROWS / 4, 256, 0, stream>>>(featt, Cs, xs, dsv, hng, hnb, ong, onb, z);
  gemm_kernel<2><<<dim3(2, 512), 256, 0, stream>>>(z, w_out, x1, nullptr, nullptr, x,
                                                   MROWS, 128, 256);
  gemm128ln_kernel<3><<<dim3(4, 256), 256, 0, stream>>>(x1, mw1, midg, nullptr, mb1,
                                                        ln2g, ln2b, MROWS, 512, 128);
  gemm_kernel<4><<<dim3(2, 512), 256, 0, stream>>>(midg, mw2, (float*)d_out, nullptr,
                                                   mb2, x1, MROWS, 128, 512);
}